// Round 1
// baseline (1582.328 us; speedup 1.0000x reference)
//
#include <hip/hip_runtime.h>
#include <math.h>

// Problem constants (match reference)
constexpr int Bc = 2, Lc = 1024, Hc = 2048, Ic = 4096, Nc = 16, Rc = 128, Kc = 4;
constexpr int Mrows = Bc * Lc;      // 2048
constexpr int Pc = Rc + 2 * Nc;     // 160
constexpr int TWOI = 2 * Ic;        // 8192
constexpr int NCH = 16;             // scan chunks
constexpr int CL = Lc / NCH;        // 64 steps per chunk

// ---------------------------------------------------------------------------
// Generic fp32 GEMM:  C[m,n] = sum_k A[m*lda+k] * W[n*ldw+k]   (A, W both K-major)
// EPI==1: C = softplus(C + bias[n])
// Dims must divide tile sizes exactly (asserted by instantiation choices).
// ---------------------------------------------------------------------------
template <int BM, int BN, int BK, int TM, int TN, int EPI>
__global__ __launch_bounds__(256) void gemm_nt(const float* __restrict__ A, int lda,
                                               const float* __restrict__ W, int ldw,
                                               float* __restrict__ C, int ldc,
                                               int Kdim, const float* __restrict__ bias) {
  constexpr int NTX = BN / TN;
  constexpr int NTY = BM / TM;
  static_assert(NTX * NTY == 256, "thread tile mismatch");
  constexpr int K4 = BK / 4;
  constexpr int ALOAD = BM * K4 / 256;
  constexpr int WLOAD = BN * K4 / 256;
  static_assert(BM * K4 % 256 == 0 && BN * K4 % 256 == 0, "load balance");

  // +4 pad keeps 16B alignment of rows and breaks bank-conflict stride
  __shared__ float As[BK][BM + 4];
  __shared__ float Ws[BK][BN + 4];

  const int tid = threadIdx.x;
  const int bm = blockIdx.y * BM;
  const int bn = blockIdx.x * BN;
  const int tx = tid % NTX, ty = tid / NTX;

  float acc[TM][TN];
#pragma unroll
  for (int i = 0; i < TM; i++)
#pragma unroll
    for (int j = 0; j < TN; j++) acc[i][j] = 0.f;

  for (int k0 = 0; k0 < Kdim; k0 += BK) {
    __syncthreads();
#pragma unroll
    for (int t = 0; t < ALOAD; t++) {
      int idx = tid + t * 256;
      int row = idx / K4, kq = idx % K4;
      float4 v = *reinterpret_cast<const float4*>(&A[(size_t)(bm + row) * lda + k0 + kq * 4]);
      As[kq * 4 + 0][row] = v.x;
      As[kq * 4 + 1][row] = v.y;
      As[kq * 4 + 2][row] = v.z;
      As[kq * 4 + 3][row] = v.w;
    }
#pragma unroll
    for (int t = 0; t < WLOAD; t++) {
      int idx = tid + t * 256;
      int row = idx / K4, kq = idx % K4;
      float4 v = *reinterpret_cast<const float4*>(&W[(size_t)(bn + row) * ldw + k0 + kq * 4]);
      Ws[kq * 4 + 0][row] = v.x;
      Ws[kq * 4 + 1][row] = v.y;
      Ws[kq * 4 + 2][row] = v.z;
      Ws[kq * 4 + 3][row] = v.w;
    }
    __syncthreads();
#pragma unroll
    for (int k = 0; k < BK; k++) {
      float a[TM], w[TN];
#pragma unroll
      for (int i = 0; i < TM; i++) a[i] = As[k][ty * TM + i];
#pragma unroll
      for (int j = 0; j < TN; j++) w[j] = Ws[k][tx * TN + j];
#pragma unroll
      for (int i = 0; i < TM; i++)
#pragma unroll
        for (int j = 0; j < TN; j++) acc[i][j] = fmaf(a[i], w[j], acc[i][j]);
    }
  }

#pragma unroll
  for (int i = 0; i < TM; i++) {
    int m = bm + ty * TM + i;
#pragma unroll
    for (int j = 0; j < TN; j++) {
      int n = bn + tx * TN + j;
      float c = acc[i][j];
      if (EPI == 1) {
        float xx = c + bias[n];
        c = (xx > 20.f) ? xx : log1pf(__expf(xx));
      }
      C[(size_t)m * ldc + n] = c;
    }
  }
}

// ---------------------------------------------------------------------------
// Causal depthwise conv (K=4) + silu.  h_in lives in proj[:, 0:I].
// u[m,i] = silu(conv_b[i] + sum_k w[i,k] * h_in[m-3+k, i])   (within-batch l>=0)
// ---------------------------------------------------------------------------
__global__ __launch_bounds__(256) void conv_silu_kernel(const float* __restrict__ proj,
                                                        const float* __restrict__ cw,
                                                        const float* __restrict__ cb,
                                                        float* __restrict__ u) {
  int t = blockIdx.x * 256 + threadIdx.x;  // t = m*I + i
  int i = t & (Ic - 1);
  int m = t >> 12;  // /Ic
  int l = m & (Lc - 1);
  float4 w4 = *reinterpret_cast<const float4*>(&cw[i * 4]);
  float wk[4] = {w4.x, w4.y, w4.z, w4.w};
  float acc = cb[i];
#pragma unroll
  for (int k = 0; k < 4; k++) {
    int ll = l - 3 + k;
    if (ll >= 0) acc = fmaf(wk[k], proj[(size_t)(m - 3 + k) * TWOI + i], acc);
  }
  u[(size_t)m * Ic + i] = acc / (1.f + __expf(-acc));
}

// ---------------------------------------------------------------------------
// Scan pass 1: per (b,i,chunk) compute (prod dA, h_end) with h_init = 0.
// sc1 layout: ((b*I + i)*NCH + c)*32 : [0..15]=Aprod, [16..31]=h_end
// ---------------------------------------------------------------------------
__global__ __launch_bounds__(256) void scan_pass1(const float* __restrict__ dt,
                                                  const float* __restrict__ u,
                                                  const float* __restrict__ ssm,
                                                  const float* __restrict__ A_log,
                                                  float* __restrict__ sc1) {
  constexpr int IB = Ic / 256;
  int ib = blockIdx.x % IB;
  int c = (blockIdx.x / IB) % NCH;
  int b = blockIdx.x / (IB * NCH);
  int i = ib * 256 + threadIdx.x;

  float Ac[Nc];
#pragma unroll
  for (int n = 0; n < Nc; n++) Ac[n] = -__expf(A_log[i * Nc + n]);
  float Ap[Nc], h[Nc];
#pragma unroll
  for (int n = 0; n < Nc; n++) { Ap[n] = 1.f; h[n] = 0.f; }

  int l0 = c * CL;
  for (int l = l0; l < l0 + CL; l++) {
    int m = b * Lc + l;
    float dtv = dt[(size_t)m * Ic + i];
    float uv = u[(size_t)m * Ic + i];
    float du = dtv * uv;
#pragma unroll
    for (int n = 0; n < Nc; n++) {
      float Bv = ssm[m * Pc + Rc + n];
      float dA = __expf(dtv * Ac[n]);
      h[n] = fmaf(dA, h[n], du * Bv);
      Ap[n] *= dA;
    }
  }
  size_t off = ((size_t)(b * Ic + i) * NCH + c) * 32;
#pragma unroll
  for (int n = 0; n < Nc; n++) {
    sc1[off + n] = Ap[n];
    sc1[off + 16 + n] = h[n];
  }
}

// Cross-chunk scan: one thread per (b,i,n); writes h_init per chunk into sc2.
__global__ __launch_bounds__(256) void scan_mid(const float* __restrict__ sc1,
                                                float* __restrict__ sc2) {
  int t = blockIdx.x * 256 + threadIdx.x;  // (b*I+i)*16 + n
  int n = t & 15;
  int bi = t >> 4;
  float h = 0.f;
  size_t base = (size_t)bi * NCH;
  for (int c = 0; c < NCH; c++) {
    sc2[(base + c) * 16 + n] = h;
    float Ap = sc1[(base + c) * 32 + n];
    float he = sc1[(base + c) * 32 + 16 + n];
    h = fmaf(Ap, h, he);
  }
}

// ---------------------------------------------------------------------------
// Scan pass 3: replay chunk from correct h_init, fuse y = sum h*C + D*u,
// multiply by silu(gate), write y into proj[:, 0:I] (h_in slots, now dead).
// ---------------------------------------------------------------------------
__global__ __launch_bounds__(256) void scan_pass3(const float* __restrict__ dt,
                                                  const float* __restrict__ u,
                                                  const float* __restrict__ ssm,
                                                  const float* __restrict__ A_log,
                                                  const float* __restrict__ Dp,
                                                  const float* __restrict__ sc2,
                                                  float* __restrict__ proj) {
  constexpr int IB = Ic / 256;
  int ib = blockIdx.x % IB;
  int c = (blockIdx.x / IB) % NCH;
  int b = blockIdx.x / (IB * NCH);
  int i = ib * 256 + threadIdx.x;

  float Ac[Nc];
#pragma unroll
  for (int n = 0; n < Nc; n++) Ac[n] = -__expf(A_log[i * Nc + n]);
  float h[Nc];
  size_t hoff = ((size_t)(b * Ic + i) * NCH + c) * 16;
#pragma unroll
  for (int n = 0; n < Nc; n++) h[n] = sc2[hoff + n];
  float Dv = Dp[i];

  int l0 = c * CL;
  for (int l = l0; l < l0 + CL; l++) {
    int m = b * Lc + l;
    float dtv = dt[(size_t)m * Ic + i];
    float uv = u[(size_t)m * Ic + i];
    float du = dtv * uv;
    float acc = Dv * uv;
#pragma unroll
    for (int n = 0; n < Nc; n++) {
      float Bv = ssm[m * Pc + Rc + n];
      float Cv = ssm[m * Pc + Rc + Nc + n];
      float dA = __expf(dtv * Ac[n]);
      h[n] = fmaf(dA, h[n], du * Bv);
      acc = fmaf(h[n], Cv, acc);
    }
    float g = proj[(size_t)m * TWOI + Ic + i];
    float sg = g / (1.f + __expf(-g));
    proj[(size_t)m * TWOI + i] = acc * sg;
  }
}

// ---------------------------------------------------------------------------
extern "C" void kernel_launch(void* const* d_in, const int* in_sizes, int n_in,
                              void* d_out, int out_size, void* d_ws, size_t ws_size,
                              hipStream_t stream) {
  const float* x = (const float*)d_in[0];
  const float* in_proj_w = (const float*)d_in[1];
  const float* conv_w = (const float*)d_in[2];
  const float* conv_b = (const float*)d_in[3];
  const float* x_proj_w = (const float*)d_in[4];
  const float* dt_proj_w = (const float*)d_in[5];
  const float* dt_proj_b = (const float*)d_in[6];
  const float* A_log = (const float*)d_in[7];
  const float* Dp = (const float*)d_in[8];
  const float* out_proj_w = (const float*)d_in[9];
  float* out = (float*)d_out;

  float* proj = (float*)d_ws;                                 // [M, 2I]  (h_in | gate); y reuses h_in slots
  float* u = proj + (size_t)Mrows * TWOI;                     // [M, I]
  float* ssm = u + (size_t)Mrows * Ic;                        // [M, 160]
  float* dt = ssm + (size_t)Mrows * Pc;                       // [M, I]
  float* sc1 = dt + (size_t)Mrows * Ic;                       // [B*I*NCH*32]
  float* sc2 = sc1 + (size_t)Bc * Ic * NCH * 32;              // [B*I*NCH*16]
  size_t need_f = (size_t)Mrows * TWOI + (size_t)Mrows * Ic + (size_t)Mrows * Pc +
                  (size_t)Mrows * Ic + (size_t)Bc * Ic * NCH * 32 + (size_t)Bc * Ic * NCH * 16;
  if (ws_size < need_f * sizeof(float)) return;  // fail safe: no OOB writes

  dim3 blk(256);

  // 1) proj = x @ in_proj_w^T : M=2048, N=8192, K=2048
  gemm_nt<128, 128, 16, 8, 8, 0><<<dim3(TWOI / 128, Mrows / 128), blk, 0, stream>>>(
      x, Hc, in_proj_w, Hc, proj, TWOI, Hc, nullptr);

  // 2) conv + silu -> u
  conv_silu_kernel<<<(size_t)Mrows * Ic / 256, blk, 0, stream>>>(proj, conv_w, conv_b, u);

  // 3) ssm = u @ x_proj_w^T : M=2048, N=160, K=4096
  gemm_nt<64, 32, 32, 4, 2, 0><<<dim3(Pc / 32, Mrows / 64), blk, 0, stream>>>(
      u, Ic, x_proj_w, Ic, ssm, Pc, Ic, nullptr);

  // 4) dt = softplus(ts @ dt_proj_w^T + b) : M=2048, N=4096, K=128
  gemm_nt<128, 128, 16, 8, 8, 1><<<dim3(Ic / 128, Mrows / 128), blk, 0, stream>>>(
      ssm, Pc, dt_proj_w, Rc, dt, Ic, Rc, dt_proj_b);

  // 5-7) chunked linear-recurrence scan, fused y/gate epilogue
  scan_pass1<<<Bc * NCH * (Ic / 256), blk, 0, stream>>>(dt, u, ssm, A_log, sc1);
  scan_mid<<<Bc * Ic * Nc / 256, blk, 0, stream>>>(sc1, sc2);
  scan_pass3<<<Bc * NCH * (Ic / 256), blk, 0, stream>>>(dt, u, ssm, A_log, Dp, sc2, proj);

  // 8) out = y @ out_proj_w^T : M=2048, N=2048, K=4096  (y strided in proj)
  gemm_nt<128, 128, 16, 8, 8, 0><<<dim3(Hc / 128, Mrows / 128), blk, 0, stream>>>(
      proj, TWOI, out_proj_w, Ic, out, Hc, Ic, nullptr);
}

// Round 3
// 548.725 us; speedup vs baseline: 2.8836x; 2.8836x over previous
//
#include <hip/hip_runtime.h>
#include <math.h>

// Problem constants (match reference)
constexpr int Bc = 2, Lc = 1024, Hc = 2048, Ic = 4096, Nc = 16, Rc = 128;
constexpr int Mrows = Bc * Lc;      // 2048
constexpr int Pc = Rc + 2 * Nc;     // 160
constexpr int TWOI = 2 * Ic;        // 8192
constexpr int NCH = 16;             // scan chunks
constexpr int CL = Lc / NCH;        // 64 steps per chunk

typedef __attribute__((ext_vector_type(8))) short s16x8;
typedef __attribute__((ext_vector_type(8))) unsigned short u16x8;
typedef __attribute__((ext_vector_type(4))) float f32x4;

__device__ __forceinline__ unsigned short f2bf(float f) {
  union { float f; unsigned int u; } v; v.f = f;
  unsigned int r = v.u + 0x7fffu + ((v.u >> 16) & 1u);  // RNE
  return (unsigned short)(r >> 16);
}

// ---------------------------------------------------------------------------
// fp32 -> bf16 bulk convert, 8 elems/thread
// ---------------------------------------------------------------------------
__global__ __launch_bounds__(256) void cvt_f32_bf16(const float* __restrict__ in,
                                                    unsigned short* __restrict__ out,
                                                    size_t n8) {
  size_t t = (size_t)blockIdx.x * 256 + threadIdx.x;
  if (t >= n8) return;
  size_t i = t * 8;
  float4 a = *reinterpret_cast<const float4*>(in + i);
  float4 b = *reinterpret_cast<const float4*>(in + i + 4);
  u16x8 o;
  o[0] = f2bf(a.x); o[1] = f2bf(a.y); o[2] = f2bf(a.z); o[3] = f2bf(a.w);
  o[4] = f2bf(b.x); o[5] = f2bf(b.y); o[6] = f2bf(b.z); o[7] = f2bf(b.w);
  *reinterpret_cast<u16x8*>(out + i) = o;
}

// ---------------------------------------------------------------------------
// bf16 MFMA GEMM (m97 structure): C[m,n] = sum_k A[m,k]*W[n,k], fp32 accum.
// 128x128 tile, 4 waves (2x2 of 64x64), BK=32, global_load_lds width 16.
// ---------------------------------------------------------------------------
__device__ __forceinline__ void gload16(const void* g, void* l) {
  __builtin_amdgcn_global_load_lds(
      (const __attribute__((address_space(1))) unsigned int*)g,
      (__attribute__((address_space(3))) unsigned int*)l, 16, 0, 0);
}

__global__ __launch_bounds__(256) void gemm_bf16_nt(const unsigned short* __restrict__ A, int lda,
                                                    const unsigned short* __restrict__ W, int ldw,
                                                    float* __restrict__ C, int ldc, int Kdim) {
  __shared__ unsigned short As[128 * 32];
  __shared__ unsigned short Bs[128 * 32];
  const int tid = threadIdx.x;
  const int lane = tid & 63;
  const int wave = tid >> 6;
  const int wr = wave >> 1, wc = wave & 1;
  const int bm = blockIdx.y * 128, bn = blockIdx.x * 128;

  f32x4 acc[4][4];
#pragma unroll
  for (int mt = 0; mt < 4; mt++)
#pragma unroll
    for (int nt = 0; nt < 4; nt++) acc[mt][nt] = (f32x4){0.f, 0.f, 0.f, 0.f};

  // staging: thread t -> row t/4 (+64 for 2nd issue), 8-elem col group t%4
  const int srow = tid >> 2;
  const int scol = (tid & 3) * 8;
  const unsigned short* Ag = A + (size_t)(bm + srow) * lda + scol;
  const unsigned short* Wg = W + (size_t)(bn + srow) * ldw + scol;
  unsigned short* Al = As + tid * 8;   // byte off = tid*16 (lane-linear per wave)
  unsigned short* Wl = Bs + tid * 8;

  // fragment read base: row = (wr*64 + lane&15), k-group (lane>>4)*8
  const unsigned short* aRd = As + (wr * 64 + (lane & 15)) * 32 + (lane >> 4) * 8;
  const unsigned short* bRd = Bs + (wc * 64 + (lane & 15)) * 32 + (lane >> 4) * 8;

  for (int k0 = 0; k0 < Kdim; k0 += 32) {
    __syncthreads();  // previous tile fully consumed
    gload16(Ag + k0, Al);
    gload16(Ag + k0 + (size_t)64 * lda, Al + 64 * 32);
    gload16(Wg + k0, Wl);
    gload16(Wg + k0 + (size_t)64 * ldw, Wl + 64 * 32);
    __syncthreads();  // compiler drains vmcnt before barrier -> tile ready
    s16x8 af[4], bw[4];
#pragma unroll
    for (int mt = 0; mt < 4; mt++) af[mt] = *reinterpret_cast<const s16x8*>(aRd + mt * 16 * 32);
#pragma unroll
    for (int nt = 0; nt < 4; nt++) bw[nt] = *reinterpret_cast<const s16x8*>(bRd + nt * 16 * 32);
#pragma unroll
    for (int mt = 0; mt < 4; mt++)
#pragma unroll
      for (int nt = 0; nt < 4; nt++)
        acc[mt][nt] = __builtin_amdgcn_mfma_f32_16x16x32_bf16(af[mt], bw[nt], acc[mt][nt], 0, 0, 0);
  }

  // C/D layout (verified m89): col = lane&15, row = (lane>>4)*4 + reg
  const int cm0 = bm + wr * 64 + (lane >> 4) * 4;
  const int cn0 = bn + wc * 64 + (lane & 15);
#pragma unroll
  for (int mt = 0; mt < 4; mt++)
#pragma unroll
    for (int nt = 0; nt < 4; nt++)
#pragma unroll
      for (int r = 0; r < 4; r++)
        C[(size_t)(cm0 + mt * 16 + r) * ldc + cn0 + nt * 16] = acc[mt][nt][r];
}

// ---------------------------------------------------------------------------
// Generic fp32 GEMM (kept for the small precision-sensitive GEMMs)
// EPI==1: C = softplus(C + bias[n])
// ---------------------------------------------------------------------------
template <int BM, int BN, int BK, int TM, int TN, int EPI>
__global__ __launch_bounds__(256) void gemm_nt(const float* __restrict__ A, int lda,
                                               const float* __restrict__ W, int ldw,
                                               float* __restrict__ C, int ldc,
                                               int Kdim, const float* __restrict__ bias) {
  constexpr int NTX = BN / TN;
  constexpr int NTY = BM / TM;
  static_assert(NTX * NTY == 256, "thread tile mismatch");
  constexpr int K4 = BK / 4;
  constexpr int ALOAD = BM * K4 / 256;
  constexpr int WLOAD = BN * K4 / 256;

  __shared__ float Asm[BK][BM + 4];
  __shared__ float Wsm[BK][BN + 4];

  const int tid = threadIdx.x;
  const int bm = blockIdx.y * BM;
  const int bn = blockIdx.x * BN;
  const int tx = tid % NTX, ty = tid / NTX;

  float acc[TM][TN];
#pragma unroll
  for (int i = 0; i < TM; i++)
#pragma unroll
    for (int j = 0; j < TN; j++) acc[i][j] = 0.f;

  for (int k0 = 0; k0 < Kdim; k0 += BK) {
    __syncthreads();
#pragma unroll
    for (int t = 0; t < ALOAD; t++) {
      int idx = tid + t * 256;
      int row = idx / K4, kq = idx % K4;
      float4 v = *reinterpret_cast<const float4*>(&A[(size_t)(bm + row) * lda + k0 + kq * 4]);
      Asm[kq * 4 + 0][row] = v.x;
      Asm[kq * 4 + 1][row] = v.y;
      Asm[kq * 4 + 2][row] = v.z;
      Asm[kq * 4 + 3][row] = v.w;
    }
#pragma unroll
    for (int t = 0; t < WLOAD; t++) {
      int idx = tid + t * 256;
      int row = idx / K4, kq = idx % K4;
      float4 v = *reinterpret_cast<const float4*>(&W[(size_t)(bn + row) * ldw + k0 + kq * 4]);
      Wsm[kq * 4 + 0][row] = v.x;
      Wsm[kq * 4 + 1][row] = v.y;
      Wsm[kq * 4 + 2][row] = v.z;
      Wsm[kq * 4 + 3][row] = v.w;
    }
    __syncthreads();
#pragma unroll
    for (int k = 0; k < BK; k++) {
      float a[TM], w[TN];
#pragma unroll
      for (int i = 0; i < TM; i++) a[i] = Asm[k][ty * TM + i];
#pragma unroll
      for (int j = 0; j < TN; j++) w[j] = Wsm[k][tx * TN + j];
#pragma unroll
      for (int i = 0; i < TM; i++)
#pragma unroll
        for (int j = 0; j < TN; j++) acc[i][j] = fmaf(a[i], w[j], acc[i][j]);
    }
  }

#pragma unroll
  for (int i = 0; i < TM; i++) {
    int m = bm + ty * TM + i;
#pragma unroll
    for (int j = 0; j < TN; j++) {
      int n = bn + tx * TN + j;
      float c = acc[i][j];
      if (EPI == 1) {
        float xx = c + bias[n];
        c = (xx > 20.f) ? xx : log1pf(__expf(xx));
      }
      C[(size_t)m * ldc + n] = c;
    }
  }
}

// ---------------------------------------------------------------------------
// Causal depthwise conv (K=4) + silu.  h_in lives in proj[:, 0:I].
// ---------------------------------------------------------------------------
__global__ __launch_bounds__(256) void conv_silu_kernel(const float* __restrict__ proj,
                                                        const float* __restrict__ cw,
                                                        const float* __restrict__ cb,
                                                        float* __restrict__ u) {
  int t = blockIdx.x * 256 + threadIdx.x;  // t = m*I + i
  int i = t & (Ic - 1);
  int m = t >> 12;  // /Ic
  int l = m & (Lc - 1);
  float4 w4 = *reinterpret_cast<const float4*>(&cw[i * 4]);
  float wk[4] = {w4.x, w4.y, w4.z, w4.w};
  float acc = cb[i];
#pragma unroll
  for (int k = 0; k < 4; k++) {
    int ll = l - 3 + k;
    if (ll >= 0) acc = fmaf(wk[k], proj[(size_t)(m - 3 + k) * TWOI + i], acc);
  }
  u[(size_t)m * Ic + i] = acc / (1.f + __expf(-acc));
}

// ---------------------------------------------------------------------------
// Scan pass 1: per (b,i,chunk) compute (prod dA, h_end) with h_init = 0.
// ---------------------------------------------------------------------------
__global__ __launch_bounds__(256) void scan_pass1(const float* __restrict__ dt,
                                                  const float* __restrict__ u,
                                                  const float* __restrict__ ssm,
                                                  const float* __restrict__ A_log,
                                                  float* __restrict__ sc1) {
  constexpr int IB = Ic / 256;
  int ib = blockIdx.x % IB;
  int c = (blockIdx.x / IB) % NCH;
  int b = blockIdx.x / (IB * NCH);
  int i = ib * 256 + threadIdx.x;

  float Ac[Nc];
#pragma unroll
  for (int n = 0; n < Nc; n++) Ac[n] = -__expf(A_log[i * Nc + n]);
  float Ap[Nc], h[Nc];
#pragma unroll
  for (int n = 0; n < Nc; n++) { Ap[n] = 1.f; h[n] = 0.f; }

  int l0 = c * CL;
  for (int l = l0; l < l0 + CL; l++) {
    int m = b * Lc + l;
    float dtv = dt[(size_t)m * Ic + i];
    float uv = u[(size_t)m * Ic + i];
    float du = dtv * uv;
#pragma unroll
    for (int n = 0; n < Nc; n++) {
      float Bv = ssm[m * Pc + Rc + n];
      float dA = __expf(dtv * Ac[n]);
      h[n] = fmaf(dA, h[n], du * Bv);
      Ap[n] *= dA;
    }
  }
  size_t off = ((size_t)(b * Ic + i) * NCH + c) * 32;
#pragma unroll
  for (int n = 0; n < Nc; n++) {
    sc1[off + n] = Ap[n];
    sc1[off + 16 + n] = h[n];
  }
}

// Cross-chunk scan: one thread per (b,i,n); writes h_init per chunk into sc2.
__global__ __launch_bounds__(256) void scan_mid(const float* __restrict__ sc1,
                                                float* __restrict__ sc2) {
  int t = blockIdx.x * 256 + threadIdx.x;  // (b*I+i)*16 + n
  int n = t & 15;
  int bi = t >> 4;
  float h = 0.f;
  size_t base = (size_t)bi * NCH;
  for (int c = 0; c < NCH; c++) {
    sc2[(base + c) * 16 + n] = h;
    float Ap = sc1[(base + c) * 32 + n];
    float he = sc1[(base + c) * 32 + 16 + n];
    h = fmaf(Ap, h, he);
  }
}

// ---------------------------------------------------------------------------
// Scan pass 3: replay chunk from h_init, fuse y = sum h*C + D*u, silu(gate),
// write y as bf16 into yb (packed [M][I]).
// ---------------------------------------------------------------------------
__global__ __launch_bounds__(256) void scan_pass3(const float* __restrict__ dt,
                                                  const float* __restrict__ u,
                                                  const float* __restrict__ ssm,
                                                  const float* __restrict__ A_log,
                                                  const float* __restrict__ Dp,
                                                  const float* __restrict__ sc2,
                                                  const float* __restrict__ proj,
                                                  unsigned short* __restrict__ yb) {
  constexpr int IB = Ic / 256;
  int ib = blockIdx.x % IB;
  int c = (blockIdx.x / IB) % NCH;
  int b = blockIdx.x / (IB * NCH);
  int i = ib * 256 + threadIdx.x;

  float Ac[Nc];
#pragma unroll
  for (int n = 0; n < Nc; n++) Ac[n] = -__expf(A_log[i * Nc + n]);
  float h[Nc];
  size_t hoff = ((size_t)(b * Ic + i) * NCH + c) * 16;
#pragma unroll
  for (int n = 0; n < Nc; n++) h[n] = sc2[hoff + n];
  float Dv = Dp[i];

  int l0 = c * CL;
  for (int l = l0; l < l0 + CL; l++) {
    int m = b * Lc + l;
    float dtv = dt[(size_t)m * Ic + i];
    float uv = u[(size_t)m * Ic + i];
    float du = dtv * uv;
    float acc = Dv * uv;
#pragma unroll
    for (int n = 0; n < Nc; n++) {
      float Bv = ssm[m * Pc + Rc + n];
      float Cv = ssm[m * Pc + Rc + Nc + n];
      float dA = __expf(dtv * Ac[n]);
      h[n] = fmaf(dA, h[n], du * Bv);
      acc = fmaf(h[n], Cv, acc);
    }
    float g = proj[(size_t)m * TWOI + Ic + i];
    float sg = g / (1.f + __expf(-g));
    yb[(size_t)m * Ic + i] = f2bf(acc * sg);
  }
}

// ---------------------------------------------------------------------------
extern "C" void kernel_launch(void* const* d_in, const int* in_sizes, int n_in,
                              void* d_out, int out_size, void* d_ws, size_t ws_size,
                              hipStream_t stream) {
  const float* x = (const float*)d_in[0];
  const float* in_proj_w = (const float*)d_in[1];
  const float* conv_w = (const float*)d_in[2];
  const float* conv_b = (const float*)d_in[3];
  const float* x_proj_w = (const float*)d_in[4];
  const float* dt_proj_w = (const float*)d_in[5];
  const float* dt_proj_b = (const float*)d_in[6];
  const float* A_log = (const float*)d_in[7];
  const float* Dp = (const float*)d_in[8];
  const float* out_proj_w = (const float*)d_in[9];
  float* out = (float*)d_out;

  // Workspace layout (with overlays; all lifetimes disjoint in stream order):
  char* base = (char*)d_ws;
  float* proj = (float*)base;            base += (size_t)Mrows * TWOI * 4;   // 64 MB
  float* u = (float*)base;                                                   // 32 MB
  unsigned short* owb = (unsigned short*)u;  // overlays u after scan_pass3
  base += (size_t)Mrows * Ic * 4;
  float* ssm = (float*)base;             base += (size_t)Mrows * Pc * 4;     // 1.3 MB
  float* dt = (float*)base;              base += (size_t)Mrows * Ic * 4;     // 32 MB
  unsigned short* xb = (unsigned short*)base; base += (size_t)Mrows * Hc * 2; // 8.4 MB
  char* wbase = base;                    base += (size_t)TWOI * Hc * 2;      // 33.5 MB
  unsigned short* wb = (unsigned short*)wbase;       // in_proj_w bf16 (dead after proj GEMM)
  float* sc1 = (float*)wbase;                        // overlays wb (16.7 MB)
  unsigned short* yb = (unsigned short*)wbase;       // overlays sc1 after scan_mid (16.7 MB)
  float* sc2 = (float*)(wbase + (size_t)Bc * Ic * NCH * 32 * 4);  // +16.7 MB, 8.4 MB
  size_t need = (size_t)(base - (char*)d_ws);
  if (ws_size < need) return;  // fail safe: no OOB writes

  dim3 blk(256);

  // 0) bf16 conversions for the big GEMM operands
  cvt_f32_bf16<<<(Mrows * (size_t)Hc / 8 + 255) / 256, blk, 0, stream>>>(x, xb, Mrows * (size_t)Hc / 8);
  cvt_f32_bf16<<<((size_t)TWOI * Hc / 8 + 255) / 256, blk, 0, stream>>>(in_proj_w, wb, (size_t)TWOI * Hc / 8);

  // 1) proj = x @ in_proj_w^T : M=2048, N=8192, K=2048 (bf16 MFMA)
  gemm_bf16_nt<<<dim3(TWOI / 128, Mrows / 128), blk, 0, stream>>>(xb, Hc, wb, Hc, proj, TWOI, Hc);

  // 2) conv + silu -> u
  conv_silu_kernel<<<(size_t)Mrows * Ic / 256, blk, 0, stream>>>(proj, conv_w, conv_b, u);

  // 3) ssm = u @ x_proj_w^T : M=2048, N=160, K=4096 (fp32 — feeds scan)
  gemm_nt<64, 32, 32, 4, 2, 0><<<dim3(Pc / 32, Mrows / 64), blk, 0, stream>>>(
      u, Ic, x_proj_w, Ic, ssm, Pc, Ic, nullptr);

  // 4) dt = softplus(ts @ dt_proj_w^T + b) : M=2048, N=4096, K=128 (fp32)
  gemm_nt<128, 128, 16, 8, 8, 1><<<dim3(Ic / 128, Mrows / 128), blk, 0, stream>>>(
      ssm, Pc, dt_proj_w, Rc, dt, Ic, Rc, dt_proj_b);

  // 5-7) chunked linear-recurrence scan, fused y/gate epilogue -> yb (bf16)
  scan_pass1<<<Bc * NCH * (Ic / 256), blk, 0, stream>>>(dt, u, ssm, A_log, sc1);
  scan_mid<<<Bc * Ic * Nc / 256, blk, 0, stream>>>(sc1, sc2);
  scan_pass3<<<Bc * NCH * (Ic / 256), blk, 0, stream>>>(dt, u, ssm, A_log, Dp, sc2, proj, yb);

  // 7b) out_proj_w -> bf16 (overlays dead u)
  cvt_f32_bf16<<<((size_t)Hc * Ic / 8 + 255) / 256, blk, 0, stream>>>(out_proj_w, owb, (size_t)Hc * Ic / 8);

  // 8) out = y @ out_proj_w^T : M=2048, N=2048, K=4096 (bf16 MFMA)
  gemm_bf16_nt<<<dim3(Hc / 128, Mrows / 128), blk, 0, stream>>>(yb, Ic, owb, Ic, out, Hc, Ic);
}

// Round 4
// 438.194 us; speedup vs baseline: 3.6110x; 1.2522x over previous
//
#include <hip/hip_runtime.h>
#include <math.h>

// Problem constants (match reference)
constexpr int Bc = 2, Lc = 1024, Hc = 2048, Ic = 4096, Nc = 16, Rc = 128;
constexpr int Mrows = Bc * Lc;      // 2048
constexpr int Pc = Rc + 2 * Nc;     // 160
constexpr int TWOI = 2 * Ic;        // 8192
constexpr int NCH = 16;             // scan chunks
constexpr int CL = Lc / NCH;        // 64 steps per chunk
constexpr int KS = 8;               // ssm GEMM k-splits
constexpr int KCH = Ic / KS;        // 512

typedef __attribute__((ext_vector_type(8))) short s16x8;
typedef __attribute__((ext_vector_type(8))) unsigned short u16x8;
typedef __attribute__((ext_vector_type(4))) float f32x4;

__device__ __forceinline__ unsigned short f2bf(float f) {
  union { float f; unsigned int u; } v; v.f = f;
  unsigned int r = v.u + 0x7fffu + ((v.u >> 16) & 1u);  // RNE
  return (unsigned short)(r >> 16);
}

// ---------------------------------------------------------------------------
// fp32 -> bf16 bulk convert, 8 elems/thread
// ---------------------------------------------------------------------------
__global__ __launch_bounds__(256) void cvt_f32_bf16(const float* __restrict__ in,
                                                    unsigned short* __restrict__ out,
                                                    size_t n8) {
  size_t t = (size_t)blockIdx.x * 256 + threadIdx.x;
  if (t >= n8) return;
  size_t i = t * 8;
  float4 a = *reinterpret_cast<const float4*>(in + i);
  float4 b = *reinterpret_cast<const float4*>(in + i + 4);
  u16x8 o;
  o[0] = f2bf(a.x); o[1] = f2bf(a.y); o[2] = f2bf(a.z); o[3] = f2bf(a.w);
  o[4] = f2bf(b.x); o[5] = f2bf(b.y); o[6] = f2bf(b.z); o[7] = f2bf(b.w);
  *reinterpret_cast<u16x8*>(out + i) = o;
}

// ---------------------------------------------------------------------------
// bf16 MFMA GEMM (m97 structure): C[m,n] = sum_k A[m,k]*W[n,k], fp32 accum.
// 128x128 tile, 4 waves (2x2 of 64x64), BK=32, global_load_lds width 16.
// ---------------------------------------------------------------------------
__device__ __forceinline__ void gload16(const void* g, void* l) {
  __builtin_amdgcn_global_load_lds(
      (const __attribute__((address_space(1))) unsigned int*)g,
      (__attribute__((address_space(3))) unsigned int*)l, 16, 0, 0);
}

__global__ __launch_bounds__(256) void gemm_bf16_nt(const unsigned short* __restrict__ A, int lda,
                                                    const unsigned short* __restrict__ W, int ldw,
                                                    float* __restrict__ C, int ldc, int Kdim) {
  __shared__ unsigned short As[128 * 32];
  __shared__ unsigned short Bs[128 * 32];
  const int tid = threadIdx.x;
  const int lane = tid & 63;
  const int wave = tid >> 6;
  const int wr = wave >> 1, wc = wave & 1;
  const int bm = blockIdx.y * 128, bn = blockIdx.x * 128;

  f32x4 acc[4][4];
#pragma unroll
  for (int mt = 0; mt < 4; mt++)
#pragma unroll
    for (int nt = 0; nt < 4; nt++) acc[mt][nt] = (f32x4){0.f, 0.f, 0.f, 0.f};

  // staging: thread t -> row t/4 (+64 for 2nd issue), 8-elem col group t%4
  const int srow = tid >> 2;
  const int scol = (tid & 3) * 8;
  const unsigned short* Ag = A + (size_t)(bm + srow) * lda + scol;
  const unsigned short* Wg = W + (size_t)(bn + srow) * ldw + scol;
  unsigned short* Al = As + tid * 8;   // byte off = tid*16 (lane-linear per wave)
  unsigned short* Wl = Bs + tid * 8;

  // fragment read base: row = (wr*64 + lane&15), k-group (lane>>4)*8
  const unsigned short* aRd = As + (wr * 64 + (lane & 15)) * 32 + (lane >> 4) * 8;
  const unsigned short* bRd = Bs + (wc * 64 + (lane & 15)) * 32 + (lane >> 4) * 8;

  for (int k0 = 0; k0 < Kdim; k0 += 32) {
    __syncthreads();  // previous tile fully consumed
    gload16(Ag + k0, Al);
    gload16(Ag + k0 + (size_t)64 * lda, Al + 64 * 32);
    gload16(Wg + k0, Wl);
    gload16(Wg + k0 + (size_t)64 * ldw, Wl + 64 * 32);
    __syncthreads();  // compiler drains vmcnt before barrier -> tile ready
    s16x8 af[4], bw[4];
#pragma unroll
    for (int mt = 0; mt < 4; mt++) af[mt] = *reinterpret_cast<const s16x8*>(aRd + mt * 16 * 32);
#pragma unroll
    for (int nt = 0; nt < 4; nt++) bw[nt] = *reinterpret_cast<const s16x8*>(bRd + nt * 16 * 32);
#pragma unroll
    for (int mt = 0; mt < 4; mt++)
#pragma unroll
      for (int nt = 0; nt < 4; nt++)
        acc[mt][nt] = __builtin_amdgcn_mfma_f32_16x16x32_bf16(af[mt], bw[nt], acc[mt][nt], 0, 0, 0);
  }

  // C/D layout (verified m89): col = lane&15, row = (lane>>4)*4 + reg
  const int cm0 = bm + wr * 64 + (lane >> 4) * 4;
  const int cn0 = bn + wc * 64 + (lane & 15);
#pragma unroll
  for (int mt = 0; mt < 4; mt++)
#pragma unroll
    for (int nt = 0; nt < 4; nt++)
#pragma unroll
      for (int r = 0; r < 4; r++)
        C[(size_t)(cm0 + mt * 16 + r) * ldc + cn0 + nt * 16] = acc[mt][nt][r];
}

// ---------------------------------------------------------------------------
// Skinny ssm GEMM: part[ks][m][n] = sum_{k in chunk ks} u[m,k]*w[n,k]
// bf16 MFMA, no LDS: A-frag + 10 B-frags direct global->reg (B is L2-hot).
// grid (32 m-tiles, KS), 4 waves = 4x16 rows, N=160 = 10 col-tiles per wave.
// ---------------------------------------------------------------------------
__global__ __launch_bounds__(256) void ssm_bf16_kernel(const unsigned short* __restrict__ ub,
                                                       const unsigned short* __restrict__ wb,
                                                       float* __restrict__ part) {
  const int tid = threadIdx.x;
  const int lane = tid & 63;
  const int wave = tid >> 6;
  const int mt = blockIdx.x;   // 0..31
  const int ks = blockIdx.y;   // 0..KS-1
  const int r15 = lane & 15;
  const int kg = (lane >> 4) * 8;

  const unsigned short* Arow = ub + (size_t)(mt * 64 + wave * 16 + r15) * Ic + ks * KCH + kg;
  const unsigned short* Brow = wb + (size_t)r15 * Ic + ks * KCH + kg;

  f32x4 acc[10];
#pragma unroll
  for (int nt = 0; nt < 10; nt++) acc[nt] = (f32x4){0.f, 0.f, 0.f, 0.f};

#pragma unroll 2
  for (int kk = 0; kk < KCH; kk += 32) {
    s16x8 af = *reinterpret_cast<const s16x8*>(Arow + kk);
#pragma unroll
    for (int nt = 0; nt < 10; nt++) {
      s16x8 bf = *reinterpret_cast<const s16x8*>(Brow + (size_t)nt * 16 * Ic + kk);
      acc[nt] = __builtin_amdgcn_mfma_f32_16x16x32_bf16(af, bf, acc[nt], 0, 0, 0);
    }
  }

  const int m0 = mt * 64 + wave * 16 + (lane >> 4) * 4;
  float* po = part + ((size_t)ks * Mrows + m0) * Pc;
#pragma unroll
  for (int nt = 0; nt < 10; nt++)
#pragma unroll
    for (int r = 0; r < 4; r++)
      po[(size_t)r * Pc + nt * 16 + r15] = acc[nt][r];
}

__global__ __launch_bounds__(256) void ssm_reduce(const float* __restrict__ part,
                                                  float* __restrict__ ssm) {
  int t = blockIdx.x * 256 + threadIdx.x;  // m*Pc + n
  float s = 0.f;
#pragma unroll
  for (int ks = 0; ks < KS; ks++) s += part[(size_t)ks * Mrows * Pc + t];
  ssm[t] = s;
}

// ---------------------------------------------------------------------------
// Generic fp32 GEMM (kept for dt: precision-sensitive softplus->exp path)
// EPI==1: C = softplus(C + bias[n])
// ---------------------------------------------------------------------------
template <int BM, int BN, int BK, int TM, int TN, int EPI>
__global__ __launch_bounds__(256) void gemm_nt(const float* __restrict__ A, int lda,
                                               const float* __restrict__ W, int ldw,
                                               float* __restrict__ C, int ldc,
                                               int Kdim, const float* __restrict__ bias) {
  constexpr int NTX = BN / TN;
  constexpr int NTY = BM / TM;
  static_assert(NTX * NTY == 256, "thread tile mismatch");
  constexpr int K4 = BK / 4;
  constexpr int ALOAD = BM * K4 / 256;
  constexpr int WLOAD = BN * K4 / 256;

  __shared__ float Asm[BK][BM + 4];
  __shared__ float Wsm[BK][BN + 4];

  const int tid = threadIdx.x;
  const int bm = blockIdx.y * BM;
  const int bn = blockIdx.x * BN;
  const int tx = tid % NTX, ty = tid / NTX;

  float acc[TM][TN];
#pragma unroll
  for (int i = 0; i < TM; i++)
#pragma unroll
    for (int j = 0; j < TN; j++) acc[i][j] = 0.f;

  for (int k0 = 0; k0 < Kdim; k0 += BK) {
    __syncthreads();
#pragma unroll
    for (int t = 0; t < ALOAD; t++) {
      int idx = tid + t * 256;
      int row = idx / K4, kq = idx % K4;
      float4 v = *reinterpret_cast<const float4*>(&A[(size_t)(bm + row) * lda + k0 + kq * 4]);
      Asm[kq * 4 + 0][row] = v.x;
      Asm[kq * 4 + 1][row] = v.y;
      Asm[kq * 4 + 2][row] = v.z;
      Asm[kq * 4 + 3][row] = v.w;
    }
#pragma unroll
    for (int t = 0; t < WLOAD; t++) {
      int idx = tid + t * 256;
      int row = idx / K4, kq = idx % K4;
      float4 v = *reinterpret_cast<const float4*>(&W[(size_t)(bn + row) * ldw + k0 + kq * 4]);
      Wsm[kq * 4 + 0][row] = v.x;
      Wsm[kq * 4 + 1][row] = v.y;
      Wsm[kq * 4 + 2][row] = v.z;
      Wsm[kq * 4 + 3][row] = v.w;
    }
    __syncthreads();
#pragma unroll
    for (int k = 0; k < BK; k++) {
      float a[TM], w[TN];
#pragma unroll
      for (int i = 0; i < TM; i++) a[i] = Asm[k][ty * TM + i];
#pragma unroll
      for (int j = 0; j < TN; j++) w[j] = Wsm[k][tx * TN + j];
#pragma unroll
      for (int i = 0; i < TM; i++)
#pragma unroll
        for (int j = 0; j < TN; j++) acc[i][j] = fmaf(a[i], w[j], acc[i][j]);
    }
  }

#pragma unroll
  for (int i = 0; i < TM; i++) {
    int m = bm + ty * TM + i;
#pragma unroll
    for (int j = 0; j < TN; j++) {
      int n = bn + tx * TN + j;
      float c = acc[i][j];
      if (EPI == 1) {
        float xx = c + bias[n];
        c = (xx > 20.f) ? xx : log1pf(__expf(xx));
      }
      C[(size_t)m * ldc + n] = c;
    }
  }
}

// ---------------------------------------------------------------------------
// Causal depthwise conv (K=4) + silu.  h_in lives in proj[:, 0:I].
// Writes u both as fp32 (scan) and bf16 (ssm GEMM input).
// ---------------------------------------------------------------------------
__global__ __launch_bounds__(256) void conv_silu_kernel(const float* __restrict__ proj,
                                                        const float* __restrict__ cw,
                                                        const float* __restrict__ cb,
                                                        float* __restrict__ u,
                                                        unsigned short* __restrict__ ub) {
  int t = blockIdx.x * 256 + threadIdx.x;  // t = m*I + i
  int i = t & (Ic - 1);
  int m = t >> 12;  // /Ic
  int l = m & (Lc - 1);
  float4 w4 = *reinterpret_cast<const float4*>(&cw[i * 4]);
  float wk[4] = {w4.x, w4.y, w4.z, w4.w};
  float acc = cb[i];
#pragma unroll
  for (int k = 0; k < 4; k++) {
    int ll = l - 3 + k;
    if (ll >= 0) acc = fmaf(wk[k], proj[(size_t)(m - 3 + k) * TWOI + i], acc);
  }
  float s = acc / (1.f + __expf(-acc));
  u[(size_t)m * Ic + i] = s;
  ub[(size_t)m * Ic + i] = f2bf(s);
}

// ---------------------------------------------------------------------------
// Scan pass 1: per (b,i,chunk) compute (prod dA, h_end) with h_init = 0.
// ---------------------------------------------------------------------------
__global__ __launch_bounds__(256) void scan_pass1(const float* __restrict__ dt,
                                                  const float* __restrict__ u,
                                                  const float* __restrict__ ssm,
                                                  const float* __restrict__ A_log,
                                                  float* __restrict__ sc1) {
  constexpr int IB = Ic / 256;
  int ib = blockIdx.x % IB;
  int c = (blockIdx.x / IB) % NCH;
  int b = blockIdx.x / (IB * NCH);
  int i = ib * 256 + threadIdx.x;

  float Ac[Nc];
#pragma unroll
  for (int n = 0; n < Nc; n++) Ac[n] = -__expf(A_log[i * Nc + n]);
  float Ap[Nc], h[Nc];
#pragma unroll
  for (int n = 0; n < Nc; n++) { Ap[n] = 1.f; h[n] = 0.f; }

  int l0 = c * CL;
  for (int l = l0; l < l0 + CL; l++) {
    int m = b * Lc + l;
    float dtv = dt[(size_t)m * Ic + i];
    float uv = u[(size_t)m * Ic + i];
    float du = dtv * uv;
#pragma unroll
    for (int n = 0; n < Nc; n++) {
      float Bv = ssm[m * Pc + Rc + n];
      float dA = __expf(dtv * Ac[n]);
      h[n] = fmaf(dA, h[n], du * Bv);
      Ap[n] *= dA;
    }
  }
  size_t off = ((size_t)(b * Ic + i) * NCH + c) * 32;
#pragma unroll
  for (int n = 0; n < Nc; n++) {
    sc1[off + n] = Ap[n];
    sc1[off + 16 + n] = h[n];
  }
}

// Cross-chunk scan: one thread per (b,i,n); writes h_init per chunk into sc2.
__global__ __launch_bounds__(256) void scan_mid(const float* __restrict__ sc1,
                                                float* __restrict__ sc2) {
  int t = blockIdx.x * 256 + threadIdx.x;  // (b*I+i)*16 + n
  int n = t & 15;
  int bi = t >> 4;
  float h = 0.f;
  size_t base = (size_t)bi * NCH;
  for (int c = 0; c < NCH; c++) {
    sc2[(base + c) * 16 + n] = h;
    float Ap = sc1[(base + c) * 32 + n];
    float he = sc1[(base + c) * 32 + 16 + n];
    h = fmaf(Ap, h, he);
  }
}

// ---------------------------------------------------------------------------
// Scan pass 3: replay chunk from h_init, fuse y = sum h*C + D*u, silu(gate),
// write y as bf16 into yb (packed [M][I]).
// ---------------------------------------------------------------------------
__global__ __launch_bounds__(256) void scan_pass3(const float* __restrict__ dt,
                                                  const float* __restrict__ u,
                                                  const float* __restrict__ ssm,
                                                  const float* __restrict__ A_log,
                                                  const float* __restrict__ Dp,
                                                  const float* __restrict__ sc2,
                                                  const float* __restrict__ proj,
                                                  unsigned short* __restrict__ yb) {
  constexpr int IB = Ic / 256;
  int ib = blockIdx.x % IB;
  int c = (blockIdx.x / IB) % NCH;
  int b = blockIdx.x / (IB * NCH);
  int i = ib * 256 + threadIdx.x;

  float Ac[Nc];
#pragma unroll
  for (int n = 0; n < Nc; n++) Ac[n] = -__expf(A_log[i * Nc + n]);
  float h[Nc];
  size_t hoff = ((size_t)(b * Ic + i) * NCH + c) * 16;
#pragma unroll
  for (int n = 0; n < Nc; n++) h[n] = sc2[hoff + n];
  float Dv = Dp[i];

  int l0 = c * CL;
  for (int l = l0; l < l0 + CL; l++) {
    int m = b * Lc + l;
    float dtv = dt[(size_t)m * Ic + i];
    float uv = u[(size_t)m * Ic + i];
    float du = dtv * uv;
    float acc = Dv * uv;
#pragma unroll
    for (int n = 0; n < Nc; n++) {
      float Bv = ssm[m * Pc + Rc + n];
      float Cv = ssm[m * Pc + Rc + Nc + n];
      float dA = __expf(dtv * Ac[n]);
      h[n] = fmaf(dA, h[n], du * Bv);
      acc = fmaf(h[n], Cv, acc);
    }
    float g = proj[(size_t)m * TWOI + Ic + i];
    float sg = g / (1.f + __expf(-g));
    yb[(size_t)m * Ic + i] = f2bf(acc * sg);
  }
}

// ---------------------------------------------------------------------------
extern "C" void kernel_launch(void* const* d_in, const int* in_sizes, int n_in,
                              void* d_out, int out_size, void* d_ws, size_t ws_size,
                              hipStream_t stream) {
  const float* x = (const float*)d_in[0];
  const float* in_proj_w = (const float*)d_in[1];
  const float* conv_w = (const float*)d_in[2];
  const float* conv_b = (const float*)d_in[3];
  const float* x_proj_w = (const float*)d_in[4];
  const float* dt_proj_w = (const float*)d_in[5];
  const float* dt_proj_b = (const float*)d_in[6];
  const float* A_log = (const float*)d_in[7];
  const float* Dp = (const float*)d_in[8];
  const float* out_proj_w = (const float*)d_in[9];
  float* out = (float*)d_out;

  // Workspace layout (overlays; all lifetimes disjoint in stream order):
  char* base = (char*)d_ws;
  float* proj = (float*)base;            base += (size_t)Mrows * TWOI * 4;   // 64 MB
  float* u = (float*)base;                                                   // 32 MB
  unsigned short* owb = (unsigned short*)u;  // overlays u after scan_pass3
  base += (size_t)Mrows * Ic * 4;
  float* ssm = (float*)base;             base += (size_t)Mrows * Pc * 4;     // 1.3 MB
  char* dtbase = base;                   base += (size_t)Mrows * Ic * 4;     // 32 MB
  float* dt = (float*)dtbase;
  float* part = (float*)dtbase;          // [KS][M][Pc] = 10.5 MB, dead before dt written
  unsigned short* xb = (unsigned short*)base; base += (size_t)Mrows * Hc * 2; // 8.4 MB
  unsigned short* wb160 = xb;            // x_proj_w bf16 (1.3 MB), after xb dead
  char* wbase = base;                    base += (size_t)TWOI * Hc * 2;      // 33.5 MB
  unsigned short* wb = (unsigned short*)wbase;   // in_proj_w bf16 (dead after proj GEMM)
  unsigned short* ubb = (unsigned short*)wbase;  // u bf16 (16.8 MB), overlays dead wb
  float* sc1 = (float*)wbase;                    // overlays ubb after ssm GEMM (16.7 MB)
  unsigned short* yb = (unsigned short*)wbase;   // overlays sc1 after scan_mid
  float* sc2 = (float*)(wbase + (size_t)Bc * Ic * NCH * 32 * 4);  // +16.7 MB, 8.4 MB
  size_t need = (size_t)(base - (char*)d_ws);
  if (ws_size < need) return;  // fail safe: no OOB writes

  dim3 blk(256);

  // 0) bf16 conversions for the proj GEMM operands
  cvt_f32_bf16<<<(Mrows * (size_t)Hc / 8 + 255) / 256, blk, 0, stream>>>(x, xb, Mrows * (size_t)Hc / 8);
  cvt_f32_bf16<<<((size_t)TWOI * Hc / 8 + 255) / 256, blk, 0, stream>>>(in_proj_w, wb, (size_t)TWOI * Hc / 8);

  // 1) proj = x @ in_proj_w^T : M=2048, N=8192, K=2048 (bf16 MFMA)
  gemm_bf16_nt<<<dim3(TWOI / 128, Mrows / 128), blk, 0, stream>>>(xb, Hc, wb, Hc, proj, TWOI, Hc);

  // 1b) x_proj_w -> bf16 (into dead xb region)
  cvt_f32_bf16<<<((size_t)Pc * Ic / 8 + 255) / 256, blk, 0, stream>>>(x_proj_w, wb160, (size_t)Pc * Ic / 8);

  // 2) conv + silu -> u (fp32) + ubb (bf16, overlays dead wb)
  conv_silu_kernel<<<(size_t)Mrows * Ic / 256, blk, 0, stream>>>(proj, conv_w, conv_b, u, ubb);

  // 3) ssm = u @ x_proj_w^T : M=2048, N=160, K=4096 (bf16 MFMA, split-K, no LDS)
  ssm_bf16_kernel<<<dim3(Mrows / 64, KS), blk, 0, stream>>>(ubb, wb160, part);
  ssm_reduce<<<Mrows * Pc / 256, blk, 0, stream>>>(part, ssm);

  // 4) dt = softplus(ts @ dt_proj_w^T + b) : M=2048, N=4096, K=128 (fp32)
  gemm_nt<128, 128, 16, 8, 8, 1><<<dim3(Ic / 128, Mrows / 128), blk, 0, stream>>>(
      ssm, Pc, dt_proj_w, Rc, dt, Ic, Rc, dt_proj_b);

  // 5-7) chunked linear-recurrence scan, fused y/gate epilogue -> yb (bf16)
  scan_pass1<<<Bc * NCH * (Ic / 256), blk, 0, stream>>>(dt, u, ssm, A_log, sc1);
  scan_mid<<<Bc * Ic * Nc / 256, blk, 0, stream>>>(sc1, sc2);
  scan_pass3<<<Bc * NCH * (Ic / 256), blk, 0, stream>>>(dt, u, ssm, A_log, Dp, sc2, proj, yb);

  // 7b) out_proj_w -> bf16 (overlays dead u)
  cvt_f32_bf16<<<((size_t)Hc * Ic / 8 + 255) / 256, blk, 0, stream>>>(out_proj_w, owb, (size_t)Hc * Ic / 8);

  // 8) out = y @ out_proj_w^T : M=2048, N=2048, K=4096 (bf16 MFMA)
  gemm_bf16_nt<<<dim3(Hc / 128, Mrows / 128), blk, 0, stream>>>(yb, Ic, owb, Ic, out, Hc, Ic);
}

// Round 5
// 417.204 us; speedup vs baseline: 3.7927x; 1.0503x over previous
//
#include <hip/hip_runtime.h>
#include <math.h>

// Problem constants (match reference)
constexpr int Bc = 2, Lc = 1024, Hc = 2048, Ic = 4096, Nc = 16, Rc = 128;
constexpr int Mrows = Bc * Lc;      // 2048
constexpr int Pc = Rc + 2 * Nc;     // 160
constexpr int TWOI = 2 * Ic;        // 8192
constexpr int NCH = 16;             // scan chunks
constexpr int CL = Lc / NCH;        // 64 steps per chunk
constexpr int KS = 8;               // ssm GEMM k-splits
constexpr int KCH = Ic / KS;        // 512

typedef __attribute__((ext_vector_type(8))) short s16x8;
typedef __attribute__((ext_vector_type(8))) unsigned short u16x8;
typedef __attribute__((ext_vector_type(4))) float f32x4;

__device__ __forceinline__ unsigned short f2bf(float f) {
  union { float f; unsigned int u; } v; v.f = f;
  unsigned int r = v.u + 0x7fffu + ((v.u >> 16) & 1u);  // RNE
  return (unsigned short)(r >> 16);
}
__device__ __forceinline__ float bf2f(unsigned short u) {
  union { unsigned int u; float f; } v; v.u = ((unsigned int)u) << 16;
  return v.f;
}

// ---------------------------------------------------------------------------
// fp32 -> bf16 bulk convert, 8 elems/thread
// ---------------------------------------------------------------------------
__global__ __launch_bounds__(256) void cvt_f32_bf16(const float* __restrict__ in,
                                                    unsigned short* __restrict__ out,
                                                    size_t n8) {
  size_t t = (size_t)blockIdx.x * 256 + threadIdx.x;
  if (t >= n8) return;
  size_t i = t * 8;
  float4 a = *reinterpret_cast<const float4*>(in + i);
  float4 b = *reinterpret_cast<const float4*>(in + i + 4);
  u16x8 o;
  o[0] = f2bf(a.x); o[1] = f2bf(a.y); o[2] = f2bf(a.z); o[3] = f2bf(a.w);
  o[4] = f2bf(b.x); o[5] = f2bf(b.y); o[6] = f2bf(b.z); o[7] = f2bf(b.w);
  *reinterpret_cast<u16x8*>(out + i) = o;
}

// ---------------------------------------------------------------------------
// bf16 MFMA GEMM (m97 structure): C[m,n] = sum_k A[m,k]*W[n,k], fp32 accum.
// 128x128 tile, 4 waves (2x2 of 64x64), BK=32, global_load_lds width 16.
// EPI==1: softplus(c + bias[n]).  OBF==1: write bf16, else fp32.
// ---------------------------------------------------------------------------
__device__ __forceinline__ void gload16(const void* g, void* l) {
  __builtin_amdgcn_global_load_lds(
      (const __attribute__((address_space(1))) unsigned int*)g,
      (__attribute__((address_space(3))) unsigned int*)l, 16, 0, 0);
}

template <int EPI, int OBF>
__global__ __launch_bounds__(256) void gemm_bf16_nt(const unsigned short* __restrict__ A, int lda,
                                                    const unsigned short* __restrict__ W, int ldw,
                                                    void* __restrict__ Cv, int ldc, int Kdim,
                                                    const float* __restrict__ bias) {
  __shared__ unsigned short As[128 * 32];
  __shared__ unsigned short Bs[128 * 32];
  const int tid = threadIdx.x;
  const int lane = tid & 63;
  const int wave = tid >> 6;
  const int wr = wave >> 1, wc = wave & 1;
  const int bm = blockIdx.y * 128, bn = blockIdx.x * 128;

  f32x4 acc[4][4];
#pragma unroll
  for (int mt = 0; mt < 4; mt++)
#pragma unroll
    for (int nt = 0; nt < 4; nt++) acc[mt][nt] = (f32x4){0.f, 0.f, 0.f, 0.f};

  const int srow = tid >> 2;
  const int scol = (tid & 3) * 8;
  const unsigned short* Ag = A + (size_t)(bm + srow) * lda + scol;
  const unsigned short* Wg = W + (size_t)(bn + srow) * ldw + scol;
  unsigned short* Al = As + tid * 8;
  unsigned short* Wl = Bs + tid * 8;

  const unsigned short* aRd = As + (wr * 64 + (lane & 15)) * 32 + (lane >> 4) * 8;
  const unsigned short* bRd = Bs + (wc * 64 + (lane & 15)) * 32 + (lane >> 4) * 8;

  for (int k0 = 0; k0 < Kdim; k0 += 32) {
    __syncthreads();
    gload16(Ag + k0, Al);
    gload16(Ag + k0 + (size_t)64 * lda, Al + 64 * 32);
    gload16(Wg + k0, Wl);
    gload16(Wg + k0 + (size_t)64 * ldw, Wl + 64 * 32);
    __syncthreads();
    s16x8 af[4], bw[4];
#pragma unroll
    for (int mt = 0; mt < 4; mt++) af[mt] = *reinterpret_cast<const s16x8*>(aRd + mt * 16 * 32);
#pragma unroll
    for (int nt = 0; nt < 4; nt++) bw[nt] = *reinterpret_cast<const s16x8*>(bRd + nt * 16 * 32);
#pragma unroll
    for (int mt = 0; mt < 4; mt++)
#pragma unroll
      for (int nt = 0; nt < 4; nt++)
        acc[mt][nt] = __builtin_amdgcn_mfma_f32_16x16x32_bf16(af[mt], bw[nt], acc[mt][nt], 0, 0, 0);
  }

  // C/D layout (verified m89): col = lane&15, row = (lane>>4)*4 + reg
  const int cm0 = bm + wr * 64 + (lane >> 4) * 4;
  const int cn0 = bn + wc * 64 + (lane & 15);
#pragma unroll
  for (int mt = 0; mt < 4; mt++)
#pragma unroll
    for (int nt = 0; nt < 4; nt++)
#pragma unroll
      for (int r = 0; r < 4; r++) {
        float c = acc[mt][nt][r];
        int n = cn0 + nt * 16;
        if (EPI == 1) {
          float xx = c + bias[n];
          c = (xx > 20.f) ? xx : log1pf(__expf(xx));
        }
        size_t idx = (size_t)(cm0 + mt * 16 + r) * ldc + n;
        if (OBF)
          ((unsigned short*)Cv)[idx] = f2bf(c);
        else
          ((float*)Cv)[idx] = c;
      }
}

// ---------------------------------------------------------------------------
// Skinny ssm GEMM: part[ks][m][n] = sum_{k in chunk ks} u[m,k]*w[n,k]
// bf16 MFMA, no LDS; B panel L2-hot.
// ---------------------------------------------------------------------------
__global__ __launch_bounds__(256) void ssm_bf16_kernel(const unsigned short* __restrict__ ub,
                                                       const unsigned short* __restrict__ wb,
                                                       float* __restrict__ part) {
  const int tid = threadIdx.x;
  const int lane = tid & 63;
  const int wave = tid >> 6;
  const int mt = blockIdx.x;   // 0..31
  const int ks = blockIdx.y;   // 0..KS-1
  const int r15 = lane & 15;
  const int kg = (lane >> 4) * 8;

  const unsigned short* Arow = ub + (size_t)(mt * 64 + wave * 16 + r15) * Ic + ks * KCH + kg;
  const unsigned short* Brow = wb + (size_t)r15 * Ic + ks * KCH + kg;

  f32x4 acc[10];
#pragma unroll
  for (int nt = 0; nt < 10; nt++) acc[nt] = (f32x4){0.f, 0.f, 0.f, 0.f};

#pragma unroll 2
  for (int kk = 0; kk < KCH; kk += 32) {
    s16x8 af = *reinterpret_cast<const s16x8*>(Arow + kk);
#pragma unroll
    for (int nt = 0; nt < 10; nt++) {
      s16x8 bf = *reinterpret_cast<const s16x8*>(Brow + (size_t)nt * 16 * Ic + kk);
      acc[nt] = __builtin_amdgcn_mfma_f32_16x16x32_bf16(af, bf, acc[nt], 0, 0, 0);
    }
  }

  const int m0 = mt * 64 + wave * 16 + (lane >> 4) * 4;
  float* po = part + ((size_t)ks * Mrows + m0) * Pc;
#pragma unroll
  for (int nt = 0; nt < 10; nt++)
#pragma unroll
    for (int r = 0; r < 4; r++)
      po[(size_t)r * Pc + nt * 16 + r15] = acc[nt][r];
}

// reduce partials -> ssm (f32) and ts (bf16, first 128 cols)
__global__ __launch_bounds__(256) void ssm_reduce(const float* __restrict__ part,
                                                  float* __restrict__ ssm,
                                                  unsigned short* __restrict__ tsb) {
  int t = blockIdx.x * 256 + threadIdx.x;  // m*Pc + n
  float s = 0.f;
#pragma unroll
  for (int ks = 0; ks < KS; ks++) s += part[(size_t)ks * Mrows * Pc + t];
  ssm[t] = s;
  int m = t / Pc, n = t - m * Pc;
  if (n < Rc) tsb[(size_t)m * Rc + n] = f2bf(s);
}

// ---------------------------------------------------------------------------
// Causal depthwise conv (K=4) + silu; reads bf16 h_in from projb, writes bf16 u.
// ---------------------------------------------------------------------------
__global__ __launch_bounds__(256) void conv_silu_kernel(const unsigned short* __restrict__ projb,
                                                        const float* __restrict__ cw,
                                                        const float* __restrict__ cb,
                                                        unsigned short* __restrict__ ub) {
  int t = blockIdx.x * 256 + threadIdx.x;  // t = m*I + i
  int i = t & (Ic - 1);
  int m = t >> 12;  // /Ic
  int l = m & (Lc - 1);
  float4 w4 = *reinterpret_cast<const float4*>(&cw[i * 4]);
  float wk[4] = {w4.x, w4.y, w4.z, w4.w};
  float acc = cb[i];
#pragma unroll
  for (int k = 0; k < 4; k++) {
    int ll = l - 3 + k;
    if (ll >= 0) acc = fmaf(wk[k], bf2f(projb[(size_t)(m - 3 + k) * TWOI + i]), acc);
  }
  float s = acc / (1.f + __expf(-acc));
  ub[(size_t)m * Ic + i] = f2bf(s);
}

// ---------------------------------------------------------------------------
// Scan pass 1: per (b,i,chunk) compute (prod dA, h_end) with h_init = 0.
// ---------------------------------------------------------------------------
__global__ __launch_bounds__(256) void scan_pass1(const float* __restrict__ dt,
                                                  const unsigned short* __restrict__ ub,
                                                  const float* __restrict__ ssm,
                                                  const float* __restrict__ A_log,
                                                  float* __restrict__ sc1) {
  constexpr int IB = Ic / 256;
  int ib = blockIdx.x % IB;
  int c = (blockIdx.x / IB) % NCH;
  int b = blockIdx.x / (IB * NCH);
  int i = ib * 256 + threadIdx.x;

  float Ac[Nc];
#pragma unroll
  for (int n = 0; n < Nc; n++) Ac[n] = -__expf(A_log[i * Nc + n]);
  float Ap[Nc], h[Nc];
#pragma unroll
  for (int n = 0; n < Nc; n++) { Ap[n] = 1.f; h[n] = 0.f; }

  int l0 = c * CL;
  for (int l = l0; l < l0 + CL; l++) {
    int m = b * Lc + l;
    float dtv = dt[(size_t)m * Ic + i];
    float uv = bf2f(ub[(size_t)m * Ic + i]);
    float du = dtv * uv;
#pragma unroll
    for (int n = 0; n < Nc; n++) {
      float Bv = ssm[m * Pc + Rc + n];
      float dA = __expf(dtv * Ac[n]);
      h[n] = fmaf(dA, h[n], du * Bv);
      Ap[n] *= dA;
    }
  }
  size_t off = ((size_t)(b * Ic + i) * NCH + c) * 32;
#pragma unroll
  for (int n = 0; n < Nc; n++) {
    sc1[off + n] = Ap[n];
    sc1[off + 16 + n] = h[n];
  }
}

// Cross-chunk scan: one thread per (b,i,n); writes h_init per chunk into sc2.
__global__ __launch_bounds__(256) void scan_mid(const float* __restrict__ sc1,
                                                float* __restrict__ sc2) {
  int t = blockIdx.x * 256 + threadIdx.x;  // (b*I+i)*16 + n
  int n = t & 15;
  int bi = t >> 4;
  float h = 0.f;
  size_t base = (size_t)bi * NCH;
  for (int c = 0; c < NCH; c++) {
    sc2[(base + c) * 16 + n] = h;
    float Ap = sc1[(base + c) * 32 + n];
    float he = sc1[(base + c) * 32 + 16 + n];
    h = fmaf(Ap, h, he);
  }
}

// ---------------------------------------------------------------------------
// Scan pass 3: replay chunk from h_init, fuse y = sum h*C + D*u, silu(gate),
// write y as bf16 into yb.
// ---------------------------------------------------------------------------
__global__ __launch_bounds__(256) void scan_pass3(const float* __restrict__ dt,
                                                  const unsigned short* __restrict__ ub,
                                                  const float* __restrict__ ssm,
                                                  const float* __restrict__ A_log,
                                                  const float* __restrict__ Dp,
                                                  const float* __restrict__ sc2,
                                                  const unsigned short* __restrict__ projb,
                                                  unsigned short* __restrict__ yb) {
  constexpr int IB = Ic / 256;
  int ib = blockIdx.x % IB;
  int c = (blockIdx.x / IB) % NCH;
  int b = blockIdx.x / (IB * NCH);
  int i = ib * 256 + threadIdx.x;

  float Ac[Nc];
#pragma unroll
  for (int n = 0; n < Nc; n++) Ac[n] = -__expf(A_log[i * Nc + n]);
  float h[Nc];
  size_t hoff = ((size_t)(b * Ic + i) * NCH + c) * 16;
#pragma unroll
  for (int n = 0; n < Nc; n++) h[n] = sc2[hoff + n];
  float Dv = Dp[i];

  int l0 = c * CL;
  for (int l = l0; l < l0 + CL; l++) {
    int m = b * Lc + l;
    float dtv = dt[(size_t)m * Ic + i];
    float uv = bf2f(ub[(size_t)m * Ic + i]);
    float du = dtv * uv;
    float acc = Dv * uv;
#pragma unroll
    for (int n = 0; n < Nc; n++) {
      float Bv = ssm[m * Pc + Rc + n];
      float Cv = ssm[m * Pc + Rc + Nc + n];
      float dA = __expf(dtv * Ac[n]);
      h[n] = fmaf(dA, h[n], du * Bv);
      acc = fmaf(h[n], Cv, acc);
    }
    float g = bf2f(projb[(size_t)m * TWOI + Ic + i]);
    float sg = g / (1.f + __expf(-g));
    yb[(size_t)m * Ic + i] = f2bf(acc * sg);
  }
}

// ---------------------------------------------------------------------------
extern "C" void kernel_launch(void* const* d_in, const int* in_sizes, int n_in,
                              void* d_out, int out_size, void* d_ws, size_t ws_size,
                              hipStream_t stream) {
  const float* x = (const float*)d_in[0];
  const float* in_proj_w = (const float*)d_in[1];
  const float* conv_w = (const float*)d_in[2];
  const float* conv_b = (const float*)d_in[3];
  const float* x_proj_w = (const float*)d_in[4];
  const float* dt_proj_w = (const float*)d_in[5];
  const float* dt_proj_b = (const float*)d_in[6];
  const float* A_log = (const float*)d_in[7];
  const float* Dp = (const float*)d_in[8];
  const float* out_proj_w = (const float*)d_in[9];
  float* out = (float*)d_out;

  // Workspace layout (overlays; lifetimes disjoint in stream order):
  char* base = (char*)d_ws;
  unsigned short* projb = (unsigned short*)base; base += (size_t)Mrows * TWOI * 2;  // 32 MB
  unsigned short* ub = (unsigned short*)base;    base += (size_t)Mrows * Ic * 2;    // 16 MB
  float* ssm = (float*)base;                     base += (size_t)Mrows * Pc * 4;    // 1.3 MB
  unsigned short* tsb = (unsigned short*)base;   base += (size_t)Mrows * Rc * 2;    // 0.5 MB
  char* dtb = base;                              base += (size_t)Mrows * Ic * 4;    // 32 MB
  float* dt = (float*)dtb;
  float* part = (float*)dtb;                 // [KS][M][Pc] = 10.5 MB, dead before dt
  unsigned short* owb = (unsigned short*)dtb;  // out_proj bf16, overlays dt after scan3
  char* xbb = base;                              base += (size_t)Mrows * Hc * 2;    // 8.4 MB
  unsigned short* xb = (unsigned short*)xbb;
  unsigned short* wb160 = (unsigned short*)xbb;                 // x_proj bf16 (1.3 MB) after xb dead
  unsigned short* dtwb = (unsigned short*)(xbb + 2 * 1024 * 1024);  // dt_proj_w bf16 (1 MB)
  char* wbase = base;                            base += (size_t)TWOI * Hc * 2;     // 33.5 MB
  unsigned short* wb = (unsigned short*)wbase;   // in_proj bf16, dead after proj GEMM
  float* sc1 = (float*)wbase;                    // 16.7 MB overlay
  unsigned short* yb = (unsigned short*)wbase;   // 16 MB overlay after scan_mid
  float* sc2 = (float*)(wbase + (size_t)Bc * Ic * NCH * 32 * 4);  // 8.4 MB
  size_t need = (size_t)(base - (char*)d_ws);
  if (ws_size < need) return;  // fail safe

  dim3 blk(256);

  // 0) bf16 conversions for proj GEMM
  cvt_f32_bf16<<<(Mrows * (size_t)Hc / 8 + 255) / 256, blk, 0, stream>>>(x, xb, Mrows * (size_t)Hc / 8);
  cvt_f32_bf16<<<((size_t)TWOI * Hc / 8 + 255) / 256, blk, 0, stream>>>(in_proj_w, wb, (size_t)TWOI * Hc / 8);

  // 1) proj = x @ in_proj_w^T (bf16 out: h_in | gate)
  gemm_bf16_nt<0, 1><<<dim3(TWOI / 128, Mrows / 128), blk, 0, stream>>>(
      xb, Hc, wb, Hc, projb, TWOI, Hc, nullptr);

  // 1b) small-weight conversions (into dead xb region)
  cvt_f32_bf16<<<((size_t)Pc * Ic / 8 + 255) / 256, blk, 0, stream>>>(x_proj_w, wb160, (size_t)Pc * Ic / 8);
  cvt_f32_bf16<<<((size_t)Ic * Rc / 8 + 255) / 256, blk, 0, stream>>>(dt_proj_w, dtwb, (size_t)Ic * Rc / 8);

  // 2) conv + silu -> ub (bf16)
  conv_silu_kernel<<<(size_t)Mrows * Ic / 256, blk, 0, stream>>>(projb, conv_w, conv_b, ub);

  // 3) ssm = u @ x_proj_w^T (split-K bf16) -> ssm f32 + ts bf16
  ssm_bf16_kernel<<<dim3(Mrows / 64, KS), blk, 0, stream>>>(ub, wb160, part);
  ssm_reduce<<<Mrows * Pc / 256, blk, 0, stream>>>(part, ssm, tsb);

  // 4) dt = softplus(ts @ dt_proj_w^T + b) (bf16 MFMA, K=128, fp32 out)
  gemm_bf16_nt<1, 0><<<dim3(Ic / 128, Mrows / 128), blk, 0, stream>>>(
      tsb, Rc, dtwb, Rc, dt, Ic, Rc, dt_proj_b);

  // 5-7) chunked scan + fused epilogue -> yb (bf16)
  scan_pass1<<<Bc * NCH * (Ic / 256), blk, 0, stream>>>(dt, ub, ssm, A_log, sc1);
  scan_mid<<<Bc * Ic * Nc / 256, blk, 0, stream>>>(sc1, sc2);
  scan_pass3<<<Bc * NCH * (Ic / 256), blk, 0, stream>>>(dt, ub, ssm, A_log, Dp, sc2, projb, yb);

  // 7b) out_proj -> bf16 (overlays dt, dead after scan3)
  cvt_f32_bf16<<<((size_t)Hc * Ic / 8 + 255) / 256, blk, 0, stream>>>(out_proj_w, owb, (size_t)Hc * Ic / 8);

  // 8) out = y @ out_proj_w^T (bf16 MFMA, fp32 out)
  gemm_bf16_nt<0, 0><<<dim3(Hc / 128, Mrows / 128), blk, 0, stream>>>(
      yb, Ic, owb, Ic, out, Hc, Ic, nullptr);
}

// Round 6
// 375.585 us; speedup vs baseline: 4.2130x; 1.1108x over previous
//
#include <hip/hip_runtime.h>
#include <math.h>

// Problem constants (match reference)
constexpr int Bc = 2, Lc = 1024, Hc = 2048, Ic = 4096, Nc = 16, Rc = 128;
constexpr int Mrows = Bc * Lc;      // 2048
constexpr int Pc = Rc + 2 * Nc;     // 160
constexpr int TWOI = 2 * Ic;        // 8192
constexpr int NCH = 16;             // scan chunks
constexpr int CL = Lc / NCH;        // 64 steps per chunk
constexpr int KS = 8;               // ssm GEMM k-splits
constexpr int KCH = Ic / KS;        // 512

typedef __attribute__((ext_vector_type(8))) short s16x8;
typedef __attribute__((ext_vector_type(8))) unsigned short u16x8;
typedef __attribute__((ext_vector_type(4))) float f32x4;

__device__ __forceinline__ unsigned short f2bf(float f) {
  union { float f; unsigned int u; } v; v.f = f;
  unsigned int r = v.u + 0x7fffu + ((v.u >> 16) & 1u);  // RNE
  return (unsigned short)(r >> 16);
}
__device__ __forceinline__ float bf2f(unsigned short u) {
  union { unsigned int u; float f; } v; v.u = ((unsigned int)u) << 16;
  return v.f;
}

__device__ __forceinline__ void gload16(const void* g, void* l) {
  __builtin_amdgcn_global_load_lds(
      (const __attribute__((address_space(1))) unsigned int*)g,
      (__attribute__((address_space(3))) unsigned int*)l, 16, 0, 0);
}

// ---------------------------------------------------------------------------
// fp32 -> bf16 bulk convert, 8 elems/thread
// ---------------------------------------------------------------------------
__global__ __launch_bounds__(256) void cvt_f32_bf16(const float* __restrict__ in,
                                                    unsigned short* __restrict__ out,
                                                    size_t n8) {
  size_t t = (size_t)blockIdx.x * 256 + threadIdx.x;
  if (t >= n8) return;
  size_t i = t * 8;
  float4 a = *reinterpret_cast<const float4*>(in + i);
  float4 b = *reinterpret_cast<const float4*>(in + i + 4);
  u16x8 o;
  o[0] = f2bf(a.x); o[1] = f2bf(a.y); o[2] = f2bf(a.z); o[3] = f2bf(a.w);
  o[4] = f2bf(b.x); o[5] = f2bf(b.y); o[6] = f2bf(b.z); o[7] = f2bf(b.w);
  *reinterpret_cast<u16x8*>(out + i) = o;
}

// ---------------------------------------------------------------------------
// 256x256 deep-pipelined bf16 GEMM (T2 swizzle + stage-early + setprio).
// 8 waves (2M x 4N), BK=64, 128 KiB LDS double-buffer, 1 barrier per K-tile.
// LDS layout per buffer (shorts): A[0..16384) = 256x64 (2 halves of 128 rows),
// B[16384..32768). Swizzle: 16B slot s within a half -> s ^ ((s>>3)&7).
// gload_lds writes linearly; source global addr pre-swizzled (rule #21).
// ---------------------------------------------------------------------------
__global__ __launch_bounds__(512, 2) void gemm256_bf16_nt(
    const unsigned short* __restrict__ A, int lda,
    const unsigned short* __restrict__ W, int ldw,
    unsigned short* __restrict__ C, int ldc, int Kdim) {
  __shared__ unsigned short lds[2 * 32768];  // 128 KiB
  const int tid = threadIdx.x;
  const int lane = tid & 63;
  const int wave = tid >> 6;
  const int wr = wave >> 2;         // 0..1 (M)
  const int wc = wave & 3;          // 0..3 (N)
  const int r15 = lane & 15;
  const int kg = lane >> 4;         // 0..3

  // XCD-bijective block swizzle (nwg % 8 == 0 for all uses)
  int gx = gridDim.x;
  int lin = blockIdx.y * gx + blockIdx.x;
  int cpx = (gx * gridDim.y) >> 3;
  int nlin = (lin & 7) * cpx + (lin >> 3);
  const int bm = (nlin / gx) * 256;
  const int bn = (nlin % gx) * 256;

  // staging source swizzle: issue slots s0 (rows 0-63), s1 (rows 64-127)
  const int s0 = tid,       j0 = s0 ^ ((s0 >> 3) & 7);
  const int s1 = 512 + tid, j1 = s1 ^ ((s1 >> 3) & 7);
  const int ar0 = j0 >> 3, ac0 = (j0 & 7) * 8;
  const int ar1 = j1 >> 3, ac1 = (j1 & 7) * 8;

  f32x4 acc[8][4];
#pragma unroll
  for (int mf = 0; mf < 8; mf++)
#pragma unroll
    for (int nf = 0; nf < 4; nf++) acc[mf][nf] = (f32x4){0.f, 0.f, 0.f, 0.f};

  const unsigned short* Abase = A + (size_t)bm * lda;
  const unsigned short* Wbase = W + (size_t)bn * ldw;

  auto stage = [&](int kt, int d) {
    const unsigned short* Ab = Abase + kt * 64;
    const unsigned short* Wb = Wbase + kt * 64;
    unsigned short* l = lds + d * 32768;
    // A halves (rows 0-127 -> [0,8192), rows 128-255 -> [8192,16384))
    gload16(Ab + (size_t)ar0 * lda + ac0,         l + s0 * 8);
    gload16(Ab + (size_t)ar1 * lda + ac1,         l + s1 * 8);
    gload16(Ab + (size_t)(128 + ar0) * lda + ac0, l + 8192 + s0 * 8);
    gload16(Ab + (size_t)(128 + ar1) * lda + ac1, l + 8192 + s1 * 8);
    // B halves
    gload16(Wb + (size_t)ar0 * ldw + ac0,         l + 16384 + s0 * 8);
    gload16(Wb + (size_t)ar1 * ldw + ac1,         l + 16384 + s1 * 8);
    gload16(Wb + (size_t)(128 + ar0) * ldw + ac0, l + 24576 + s0 * 8);
    gload16(Wb + (size_t)(128 + ar1) * ldw + ac1, l + 24576 + s1 * 8);
  };

  const int abase = wr * 8192;                    // A-half for this wave
  const int bbase = 16384 + (wc >> 1) * 8192;     // B-half
  const int brow0 = (wc & 1) * 64;                // row base within B-half
  const int sw7 = r15 & 7;                        // swizzle row bits

  const int NT = Kdim >> 6;
  stage(0, 0);
  __syncthreads();  // compiler drains vmcnt before barrier

  for (int t = 0; t < NT; t++) {
    const int d = t & 1;
    if (t + 1 < NT) stage(t + 1, d ^ 1);  // issue early: ~4 MFMA-phases of lead
    const unsigned short* lb = lds + d * 32768;
    s16x8 afr[4], bfr[4];
#pragma unroll
    for (int kk = 0; kk < 2; kk++) {
      const int swzk = ((kk * 4 + kg) ^ sw7) * 8;  // swizzled 16B slot -> shorts
      // B frags nf0-3 for this kk
#pragma unroll
      for (int nf = 0; nf < 4; nf++) {
        int rb = brow0 + nf * 16 + r15;
        bfr[nf] = *reinterpret_cast<const s16x8*>(lb + bbase + rb * 64 + swzk);
      }
      // phase A: mf 0-3
#pragma unroll
      for (int mf = 0; mf < 4; mf++) {
        int ra = mf * 16 + r15;
        afr[mf] = *reinterpret_cast<const s16x8*>(lb + abase + ra * 64 + swzk);
      }
      __builtin_amdgcn_s_setprio(1);
#pragma unroll
      for (int mf = 0; mf < 4; mf++)
#pragma unroll
        for (int nf = 0; nf < 4; nf++)
          acc[mf][nf] = __builtin_amdgcn_mfma_f32_16x16x32_bf16(afr[mf], bfr[nf], acc[mf][nf], 0, 0, 0);
      __builtin_amdgcn_s_setprio(0);
      // phase B: mf 4-7
#pragma unroll
      for (int mf = 0; mf < 4; mf++) {
        int ra = (mf + 4) * 16 + r15;
        afr[mf] = *reinterpret_cast<const s16x8*>(lb + abase + ra * 64 + swzk);
      }
      __builtin_amdgcn_s_setprio(1);
#pragma unroll
      for (int mf = 0; mf < 4; mf++)
#pragma unroll
        for (int nf = 0; nf < 4; nf++)
          acc[mf + 4][nf] = __builtin_amdgcn_mfma_f32_16x16x32_bf16(afr[mf], bfr[nf], acc[mf + 4][nf], 0, 0, 0);
      __builtin_amdgcn_s_setprio(0);
    }
    __syncthreads();  // drains stage(t+1) loads (issued a full tile ago) + buf handoff
  }

  // C/D layout: col = lane&15, row = (lane>>4)*4 + reg
  const int cm0 = bm + wr * 128 + kg * 4;
  const int cn0 = bn + wc * 64 + r15;
#pragma unroll
  for (int mf = 0; mf < 8; mf++)
#pragma unroll
    for (int nf = 0; nf < 4; nf++)
#pragma unroll
      for (int r = 0; r < 4; r++)
        C[(size_t)(cm0 + mf * 16 + r) * ldc + cn0 + nf * 16] = f2bf(acc[mf][nf][r]);
}

// ---------------------------------------------------------------------------
// bf16 MFMA GEMM (m97 structure) — kept for out GEMM (N=2048) and dt GEMM.
// EPI==1: softplus(c + bias[n]).  OBF==1: write bf16, else fp32.
// ---------------------------------------------------------------------------
template <int EPI, int OBF>
__global__ __launch_bounds__(256) void gemm_bf16_nt(const unsigned short* __restrict__ A, int lda,
                                                    const unsigned short* __restrict__ W, int ldw,
                                                    void* __restrict__ Cv, int ldc, int Kdim,
                                                    const float* __restrict__ bias) {
  __shared__ unsigned short As[128 * 32];
  __shared__ unsigned short Bs[128 * 32];
  const int tid = threadIdx.x;
  const int lane = tid & 63;
  const int wave = tid >> 6;
  const int wr = wave >> 1, wc = wave & 1;
  const int bm = blockIdx.y * 128, bn = blockIdx.x * 128;

  f32x4 acc[4][4];
#pragma unroll
  for (int mt = 0; mt < 4; mt++)
#pragma unroll
    for (int nt = 0; nt < 4; nt++) acc[mt][nt] = (f32x4){0.f, 0.f, 0.f, 0.f};

  const int srow = tid >> 2;
  const int scol = (tid & 3) * 8;
  const unsigned short* Ag = A + (size_t)(bm + srow) * lda + scol;
  const unsigned short* Wg = W + (size_t)(bn + srow) * ldw + scol;
  unsigned short* Al = As + tid * 8;
  unsigned short* Wl = Bs + tid * 8;

  const unsigned short* aRd = As + (wr * 64 + (lane & 15)) * 32 + (lane >> 4) * 8;
  const unsigned short* bRd = Bs + (wc * 64 + (lane & 15)) * 32 + (lane >> 4) * 8;

  for (int k0 = 0; k0 < Kdim; k0 += 32) {
    __syncthreads();
    gload16(Ag + k0, Al);
    gload16(Ag + k0 + (size_t)64 * lda, Al + 64 * 32);
    gload16(Wg + k0, Wl);
    gload16(Wg + k0 + (size_t)64 * ldw, Wl + 64 * 32);
    __syncthreads();
    s16x8 af[4], bw[4];
#pragma unroll
    for (int mt = 0; mt < 4; mt++) af[mt] = *reinterpret_cast<const s16x8*>(aRd + mt * 16 * 32);
#pragma unroll
    for (int nt = 0; nt < 4; nt++) bw[nt] = *reinterpret_cast<const s16x8*>(bRd + nt * 16 * 32);
#pragma unroll
    for (int mt = 0; mt < 4; mt++)
#pragma unroll
      for (int nt = 0; nt < 4; nt++)
        acc[mt][nt] = __builtin_amdgcn_mfma_f32_16x16x32_bf16(af[mt], bw[nt], acc[mt][nt], 0, 0, 0);
  }

  const int cm0 = bm + wr * 64 + (lane >> 4) * 4;
  const int cn0 = bn + wc * 64 + (lane & 15);
#pragma unroll
  for (int mt = 0; mt < 4; mt++)
#pragma unroll
    for (int nt = 0; nt < 4; nt++)
#pragma unroll
      for (int r = 0; r < 4; r++) {
        float c = acc[mt][nt][r];
        int n = cn0 + nt * 16;
        if (EPI == 1) {
          float xx = c + bias[n];
          c = (xx > 20.f) ? xx : log1pf(__expf(xx));
        }
        size_t idx = (size_t)(cm0 + mt * 16 + r) * ldc + n;
        if (OBF)
          ((unsigned short*)Cv)[idx] = f2bf(c);
        else
          ((float*)Cv)[idx] = c;
      }
}

// ---------------------------------------------------------------------------
// Skinny ssm GEMM: part[ks][m][n] = sum_{k in chunk ks} u[m,k]*w[n,k]
// ---------------------------------------------------------------------------
__global__ __launch_bounds__(256) void ssm_bf16_kernel(const unsigned short* __restrict__ ub,
                                                       const unsigned short* __restrict__ wb,
                                                       float* __restrict__ part) {
  const int tid = threadIdx.x;
  const int lane = tid & 63;
  const int wave = tid >> 6;
  const int mt = blockIdx.x;
  const int ks = blockIdx.y;
  const int r15 = lane & 15;
  const int kg = (lane >> 4) * 8;

  const unsigned short* Arow = ub + (size_t)(mt * 64 + wave * 16 + r15) * Ic + ks * KCH + kg;
  const unsigned short* Brow = wb + (size_t)r15 * Ic + ks * KCH + kg;

  f32x4 acc[10];
#pragma unroll
  for (int nt = 0; nt < 10; nt++) acc[nt] = (f32x4){0.f, 0.f, 0.f, 0.f};

#pragma unroll 2
  for (int kk = 0; kk < KCH; kk += 32) {
    s16x8 af = *reinterpret_cast<const s16x8*>(Arow + kk);
#pragma unroll
    for (int nt = 0; nt < 10; nt++) {
      s16x8 bf = *reinterpret_cast<const s16x8*>(Brow + (size_t)nt * 16 * Ic + kk);
      acc[nt] = __builtin_amdgcn_mfma_f32_16x16x32_bf16(af, bf, acc[nt], 0, 0, 0);
    }
  }

  const int m0 = mt * 64 + wave * 16 + (lane >> 4) * 4;
  float* po = part + ((size_t)ks * Mrows + m0) * Pc;
#pragma unroll
  for (int nt = 0; nt < 10; nt++)
#pragma unroll
    for (int r = 0; r < 4; r++)
      po[(size_t)r * Pc + nt * 16 + r15] = acc[nt][r];
}

__global__ __launch_bounds__(256) void ssm_reduce(const float* __restrict__ part,
                                                  float* __restrict__ ssm,
                                                  unsigned short* __restrict__ tsb) {
  int t = blockIdx.x * 256 + threadIdx.x;
  float s = 0.f;
#pragma unroll
  for (int ks = 0; ks < KS; ks++) s += part[(size_t)ks * Mrows * Pc + t];
  ssm[t] = s;
  int m = t / Pc, n = t - m * Pc;
  if (n < Rc) tsb[(size_t)m * Rc + n] = f2bf(s);
}

// ---------------------------------------------------------------------------
// Causal depthwise conv (K=4) + silu; bf16 in/out.
// ---------------------------------------------------------------------------
__global__ __launch_bounds__(256) void conv_silu_kernel(const unsigned short* __restrict__ projb,
                                                        const float* __restrict__ cw,
                                                        const float* __restrict__ cb,
                                                        unsigned short* __restrict__ ub) {
  int t = blockIdx.x * 256 + threadIdx.x;
  int i = t & (Ic - 1);
  int m = t >> 12;
  int l = m & (Lc - 1);
  float4 w4 = *reinterpret_cast<const float4*>(&cw[i * 4]);
  float wk[4] = {w4.x, w4.y, w4.z, w4.w};
  float acc = cb[i];
#pragma unroll
  for (int k = 0; k < 4; k++) {
    int ll = l - 3 + k;
    if (ll >= 0) acc = fmaf(wk[k], bf2f(projb[(size_t)(m - 3 + k) * TWOI + i]), acc);
  }
  float s = acc / (1.f + __expf(-acc));
  ub[(size_t)m * Ic + i] = f2bf(s);
}

// ---------------------------------------------------------------------------
// Scan pass 1
// ---------------------------------------------------------------------------
__global__ __launch_bounds__(256) void scan_pass1(const float* __restrict__ dt,
                                                  const unsigned short* __restrict__ ub,
                                                  const float* __restrict__ ssm,
                                                  const float* __restrict__ A_log,
                                                  float* __restrict__ sc1) {
  constexpr int IB = Ic / 256;
  int ib = blockIdx.x % IB;
  int c = (blockIdx.x / IB) % NCH;
  int b = blockIdx.x / (IB * NCH);
  int i = ib * 256 + threadIdx.x;

  float Ac[Nc];
#pragma unroll
  for (int n = 0; n < Nc; n++) Ac[n] = -__expf(A_log[i * Nc + n]);
  float Ap[Nc], h[Nc];
#pragma unroll
  for (int n = 0; n < Nc; n++) { Ap[n] = 1.f; h[n] = 0.f; }

  int l0 = c * CL;
  for (int l = l0; l < l0 + CL; l++) {
    int m = b * Lc + l;
    float dtv = dt[(size_t)m * Ic + i];
    float uv = bf2f(ub[(size_t)m * Ic + i]);
    float du = dtv * uv;
#pragma unroll
    for (int n = 0; n < Nc; n++) {
      float Bv = ssm[m * Pc + Rc + n];
      float dA = __expf(dtv * Ac[n]);
      h[n] = fmaf(dA, h[n], du * Bv);
      Ap[n] *= dA;
    }
  }
  size_t off = ((size_t)(b * Ic + i) * NCH + c) * 32;
#pragma unroll
  for (int n = 0; n < Nc; n++) {
    sc1[off + n] = Ap[n];
    sc1[off + 16 + n] = h[n];
  }
}

__global__ __launch_bounds__(256) void scan_mid(const float* __restrict__ sc1,
                                                float* __restrict__ sc2) {
  int t = blockIdx.x * 256 + threadIdx.x;
  int n = t & 15;
  int bi = t >> 4;
  float h = 0.f;
  size_t base = (size_t)bi * NCH;
  for (int c = 0; c < NCH; c++) {
    sc2[(base + c) * 16 + n] = h;
    float Ap = sc1[(base + c) * 32 + n];
    float he = sc1[(base + c) * 32 + 16 + n];
    h = fmaf(Ap, h, he);
  }
}

// ---------------------------------------------------------------------------
// Scan pass 3
// ---------------------------------------------------------------------------
__global__ __launch_bounds__(256) void scan_pass3(const float* __restrict__ dt,
                                                  const unsigned short* __restrict__ ub,
                                                  const float* __restrict__ ssm,
                                                  const float* __restrict__ A_log,
                                                  const float* __restrict__ Dp,
                                                  const float* __restrict__ sc2,
                                                  const unsigned short* __restrict__ projb,
                                                  unsigned short* __restrict__ yb) {
  constexpr int IB = Ic / 256;
  int ib = blockIdx.x % IB;
  int c = (blockIdx.x / IB) % NCH;
  int b = blockIdx.x / (IB * NCH);
  int i = ib * 256 + threadIdx.x;

  float Ac[Nc];
#pragma unroll
  for (int n = 0; n < Nc; n++) Ac[n] = -__expf(A_log[i * Nc + n]);
  float h[Nc];
  size_t hoff = ((size_t)(b * Ic + i) * NCH + c) * 16;
#pragma unroll
  for (int n = 0; n < Nc; n++) h[n] = sc2[hoff + n];
  float Dv = Dp[i];

  int l0 = c * CL;
  for (int l = l0; l < l0 + CL; l++) {
    int m = b * Lc + l;
    float dtv = dt[(size_t)m * Ic + i];
    float uv = bf2f(ub[(size_t)m * Ic + i]);
    float du = dtv * uv;
    float acc = Dv * uv;
#pragma unroll
    for (int n = 0; n < Nc; n++) {
      float Bv = ssm[m * Pc + Rc + n];
      float Cv = ssm[m * Pc + Rc + Nc + n];
      float dA = __expf(dtv * Ac[n]);
      h[n] = fmaf(dA, h[n], du * Bv);
      acc = fmaf(h[n], Cv, acc);
    }
    float g = bf2f(projb[(size_t)m * TWOI + Ic + i]);
    float sg = g / (1.f + __expf(-g));
    yb[(size_t)m * Ic + i] = f2bf(acc * sg);
  }
}

// ---------------------------------------------------------------------------
extern "C" void kernel_launch(void* const* d_in, const int* in_sizes, int n_in,
                              void* d_out, int out_size, void* d_ws, size_t ws_size,
                              hipStream_t stream) {
  const float* x = (const float*)d_in[0];
  const float* in_proj_w = (const float*)d_in[1];
  const float* conv_w = (const float*)d_in[2];
  const float* conv_b = (const float*)d_in[3];
  const float* x_proj_w = (const float*)d_in[4];
  const float* dt_proj_w = (const float*)d_in[5];
  const float* dt_proj_b = (const float*)d_in[6];
  const float* A_log = (const float*)d_in[7];
  const float* Dp = (const float*)d_in[8];
  const float* out_proj_w = (const float*)d_in[9];
  float* out = (float*)d_out;

  // Workspace layout (overlays; lifetimes disjoint in stream order):
  char* base = (char*)d_ws;
  unsigned short* projb = (unsigned short*)base; base += (size_t)Mrows * TWOI * 2;  // 32 MB
  unsigned short* ub = (unsigned short*)base;    base += (size_t)Mrows * Ic * 2;    // 16 MB
  float* ssm = (float*)base;                     base += (size_t)Mrows * Pc * 4;    // 1.3 MB
  unsigned short* tsb = (unsigned short*)base;   base += (size_t)Mrows * Rc * 2;    // 0.5 MB
  char* dtb = base;                              base += (size_t)Mrows * Ic * 4;    // 32 MB
  float* dt = (float*)dtb;
  float* part = (float*)dtb;                   // [KS][M][Pc], dead before dt
  unsigned short* owb = (unsigned short*)dtb;  // out_proj bf16, overlays dt after scan3
  char* xbb = base;                              base += (size_t)Mrows * Hc * 2;    // 8.4 MB
  unsigned short* xb = (unsigned short*)xbb;
  unsigned short* wb160 = (unsigned short*)xbb;
  unsigned short* dtwb = (unsigned short*)(xbb + 2 * 1024 * 1024);
  char* wbase = base;                            base += (size_t)TWOI * Hc * 2;     // 33.5 MB
  unsigned short* wb = (unsigned short*)wbase;
  float* sc1 = (float*)wbase;
  unsigned short* yb = (unsigned short*)wbase;
  float* sc2 = (float*)(wbase + (size_t)Bc * Ic * NCH * 32 * 4);
  size_t need = (size_t)(base - (char*)d_ws);
  if (ws_size < need) return;

  dim3 blk(256);

  // 0) bf16 conversions for proj GEMM
  cvt_f32_bf16<<<(Mrows * (size_t)Hc / 8 + 255) / 256, blk, 0, stream>>>(x, xb, Mrows * (size_t)Hc / 8);
  cvt_f32_bf16<<<((size_t)TWOI * Hc / 8 + 255) / 256, blk, 0, stream>>>(in_proj_w, wb, (size_t)TWOI * Hc / 8);

  // 1) proj = x @ in_proj_w^T (256^2 deep-pipelined bf16 GEMM, bf16 out)
  gemm256_bf16_nt<<<dim3(TWOI / 256, Mrows / 256), dim3(512), 0, stream>>>(
      xb, Hc, wb, Hc, projb, TWOI, Hc);

  // 1b) small-weight conversions (into dead xb region)
  cvt_f32_bf16<<<((size_t)Pc * Ic / 8 + 255) / 256, blk, 0, stream>>>(x_proj_w, wb160, (size_t)Pc * Ic / 8);
  cvt_f32_bf16<<<((size_t)Ic * Rc / 8 + 255) / 256, blk, 0, stream>>>(dt_proj_w, dtwb, (size_t)Ic * Rc / 8);

  // 2) conv + silu -> ub (bf16)
  conv_silu_kernel<<<(size_t)Mrows * Ic / 256, blk, 0, stream>>>(projb, conv_w, conv_b, ub);

  // 3) ssm = u @ x_proj_w^T (split-K bf16) -> ssm f32 + ts bf16
  ssm_bf16_kernel<<<dim3(Mrows / 64, KS), blk, 0, stream>>>(ub, wb160, part);
  ssm_reduce<<<Mrows * Pc / 256, blk, 0, stream>>>(part, ssm, tsb);

  // 4) dt = softplus(ts @ dt_proj_w^T + b) (bf16 MFMA, K=128, fp32 out)
  gemm_bf16_nt<1, 0><<<dim3(Ic / 128, Mrows / 128), blk, 0, stream>>>(
      tsb, Rc, dtwb, Rc, dt, Ic, Rc, dt_proj_b);

  // 5-7) chunked scan + fused epilogue -> yb (bf16)
  scan_pass1<<<Bc * NCH * (Ic / 256), blk, 0, stream>>>(dt, ub, ssm, A_log, sc1);
  scan_mid<<<Bc * Ic * Nc / 256, blk, 0, stream>>>(sc1, sc2);
  scan_pass3<<<Bc * NCH * (Ic / 256), blk, 0, stream>>>(dt, ub, ssm, A_log, Dp, sc2, projb, yb);

  // 7b) out_proj -> bf16 (overlays dt, dead after scan3)
  cvt_f32_bf16<<<((size_t)Hc * Ic / 8 + 255) / 256, blk, 0, stream>>>(out_proj_w, owb, (size_t)Hc * Ic / 8);

  // 8) out = y @ out_proj_w^T (bf16 MFMA, fp32 out)
  gemm_bf16_nt<0, 0><<<dim3(Hc / 128, Mrows / 128), blk, 0, stream>>>(
      yb, Ic, owb, Ic, out, Hc, Ic, nullptr);
}

// Round 7
// 340.415 us; speedup vs baseline: 4.6482x; 1.1033x over previous
//
#include <hip/hip_runtime.h>
#include <math.h>

// Problem constants (match reference)
constexpr int Bc = 2, Lc = 1024, Hc = 2048, Ic = 4096, Nc = 16, Rc = 128;
constexpr int Mrows = Bc * Lc;      // 2048
constexpr int Pc = Rc + 2 * Nc;     // 160
constexpr int TWOI = 2 * Ic;        // 8192
constexpr int NCH = 16;             // scan chunks
constexpr int CL = Lc / NCH;        // 64 steps per chunk
constexpr int KS = 8;               // ssm GEMM k-splits
constexpr int KCH = Ic / KS;        // 512

typedef __attribute__((ext_vector_type(8))) short s16x8;
typedef __attribute__((ext_vector_type(8))) unsigned short u16x8;
typedef __attribute__((ext_vector_type(4))) float f32x4;

__device__ __forceinline__ unsigned short f2bf(float f) {
  union { float f; unsigned int u; } v; v.f = f;
  unsigned int r = v.u + 0x7fffu + ((v.u >> 16) & 1u);  // RNE
  return (unsigned short)(r >> 16);
}
__device__ __forceinline__ float bf2f(unsigned short u) {
  union { unsigned int u; float f; } v; v.u = ((unsigned int)u) << 16;
  return v.f;
}

__device__ __forceinline__ void gload16(const void* g, void* l) {
  __builtin_amdgcn_global_load_lds(
      (const __attribute__((address_space(1))) unsigned int*)g,
      (__attribute__((address_space(3))) unsigned int*)l, 16, 0, 0);
}

// ---------------------------------------------------------------------------
// fp32 -> bf16 bulk convert, 8 elems/thread
// ---------------------------------------------------------------------------
__global__ __launch_bounds__(256) void cvt_f32_bf16(const float* __restrict__ in,
                                                    unsigned short* __restrict__ out,
                                                    size_t n8) {
  size_t t = (size_t)blockIdx.x * 256 + threadIdx.x;
  if (t >= n8) return;
  size_t i = t * 8;
  float4 a = *reinterpret_cast<const float4*>(in + i);
  float4 b = *reinterpret_cast<const float4*>(in + i + 4);
  u16x8 o;
  o[0] = f2bf(a.x); o[1] = f2bf(a.y); o[2] = f2bf(a.z); o[3] = f2bf(a.w);
  o[4] = f2bf(b.x); o[5] = f2bf(b.y); o[6] = f2bf(b.z); o[7] = f2bf(b.w);
  *reinterpret_cast<u16x8*>(out + i) = o;
}

// ---------------------------------------------------------------------------
// 256x256 deep-pipelined bf16 GEMM (T2 swizzle + stage-early + setprio).
// 8 waves (2M x 4N), BK=64, 128 KiB LDS double-buffer, 1 barrier per K-tile.
// Split-K via blockIdx.z: koff = z*Kdim, output pointer Cz per split.
// OBF==1: bf16 output, else fp32 (partials).
// ---------------------------------------------------------------------------
template <int OBF>
__global__ __launch_bounds__(512, 2) void gemm256_bf16_nt(
    const unsigned short* __restrict__ A, int lda,
    const unsigned short* __restrict__ W, int ldw,
    void* C0, void* C1, void* C2, void* C3, int ldc, int Kdim) {
  __shared__ unsigned short lds[2 * 32768];  // 128 KiB
  const int tid = threadIdx.x;
  const int lane = tid & 63;
  const int wave = tid >> 6;
  const int wr = wave >> 2;         // 0..1 (M)
  const int wc = wave & 3;          // 0..3 (N)
  const int r15 = lane & 15;
  const int kg = lane >> 4;         // 0..3

  const int ks = blockIdx.z;
  void* Cv = (ks == 0) ? C0 : (ks == 1) ? C1 : (ks == 2) ? C2 : C3;
  const int koff = ks * Kdim;

  // XCD-bijective block swizzle within each z-slice (nwg per slice % 8 == 0)
  int gx = gridDim.x;
  int lin = blockIdx.y * gx + blockIdx.x;
  int cpx = (gx * gridDim.y) >> 3;
  int nlin = (lin & 7) * cpx + (lin >> 3);
  const int bm = (nlin / gx) * 256;
  const int bn = (nlin % gx) * 256;

  // staging source swizzle: issue slots s0 (rows 0-63), s1 (rows 64-127)
  const int s0 = tid,       j0 = s0 ^ ((s0 >> 3) & 7);
  const int s1 = 512 + tid, j1 = s1 ^ ((s1 >> 3) & 7);
  const int ar0 = j0 >> 3, ac0 = (j0 & 7) * 8;
  const int ar1 = j1 >> 3, ac1 = (j1 & 7) * 8;

  f32x4 acc[8][4];
#pragma unroll
  for (int mf = 0; mf < 8; mf++)
#pragma unroll
    for (int nf = 0; nf < 4; nf++) acc[mf][nf] = (f32x4){0.f, 0.f, 0.f, 0.f};

  const unsigned short* Abase = A + (size_t)bm * lda + koff;
  const unsigned short* Wbase = W + (size_t)bn * ldw + koff;

  auto stage = [&](int kt, int d) {
    const unsigned short* Ab = Abase + kt * 64;
    const unsigned short* Wb = Wbase + kt * 64;
    unsigned short* l = lds + d * 32768;
    gload16(Ab + (size_t)ar0 * lda + ac0,         l + s0 * 8);
    gload16(Ab + (size_t)ar1 * lda + ac1,         l + s1 * 8);
    gload16(Ab + (size_t)(128 + ar0) * lda + ac0, l + 8192 + s0 * 8);
    gload16(Ab + (size_t)(128 + ar1) * lda + ac1, l + 8192 + s1 * 8);
    gload16(Wb + (size_t)ar0 * ldw + ac0,         l + 16384 + s0 * 8);
    gload16(Wb + (size_t)ar1 * ldw + ac1,         l + 16384 + s1 * 8);
    gload16(Wb + (size_t)(128 + ar0) * ldw + ac0, l + 24576 + s0 * 8);
    gload16(Wb + (size_t)(128 + ar1) * ldw + ac1, l + 24576 + s1 * 8);
  };

  const int abase = wr * 8192;                    // A-half for this wave
  const int bbase = 16384 + (wc >> 1) * 8192;     // B-half
  const int brow0 = (wc & 1) * 64;                // row base within B-half
  const int sw7 = r15 & 7;                        // swizzle row bits

  const int NT = Kdim >> 6;
  stage(0, 0);
  __syncthreads();

  for (int t = 0; t < NT; t++) {
    const int d = t & 1;
    if (t + 1 < NT) stage(t + 1, d ^ 1);  // issue early
    const unsigned short* lb = lds + d * 32768;
    s16x8 afr[4], bfr[4];
#pragma unroll
    for (int kk = 0; kk < 2; kk++) {
      const int swzk = ((kk * 4 + kg) ^ sw7) * 8;
#pragma unroll
      for (int nf = 0; nf < 4; nf++) {
        int rb = brow0 + nf * 16 + r15;
        bfr[nf] = *reinterpret_cast<const s16x8*>(lb + bbase + rb * 64 + swzk);
      }
#pragma unroll
      for (int mf = 0; mf < 4; mf++) {
        int ra = mf * 16 + r15;
        afr[mf] = *reinterpret_cast<const s16x8*>(lb + abase + ra * 64 + swzk);
      }
      __builtin_amdgcn_s_setprio(1);
#pragma unroll
      for (int mf = 0; mf < 4; mf++)
#pragma unroll
        for (int nf = 0; nf < 4; nf++)
          acc[mf][nf] = __builtin_amdgcn_mfma_f32_16x16x32_bf16(afr[mf], bfr[nf], acc[mf][nf], 0, 0, 0);
      __builtin_amdgcn_s_setprio(0);
#pragma unroll
      for (int mf = 0; mf < 4; mf++) {
        int ra = (mf + 4) * 16 + r15;
        afr[mf] = *reinterpret_cast<const s16x8*>(lb + abase + ra * 64 + swzk);
      }
      __builtin_amdgcn_s_setprio(1);
#pragma unroll
      for (int mf = 0; mf < 4; mf++)
#pragma unroll
        for (int nf = 0; nf < 4; nf++)
          acc[mf + 4][nf] = __builtin_amdgcn_mfma_f32_16x16x32_bf16(afr[mf], bfr[nf], acc[mf + 4][nf], 0, 0, 0);
      __builtin_amdgcn_s_setprio(0);
    }
    __syncthreads();
  }

  // C/D layout: col = lane&15, row = (lane>>4)*4 + reg
  const int cm0 = bm + wr * 128 + kg * 4;
  const int cn0 = bn + wc * 64 + r15;
#pragma unroll
  for (int mf = 0; mf < 8; mf++)
#pragma unroll
    for (int nf = 0; nf < 4; nf++)
#pragma unroll
      for (int r = 0; r < 4; r++) {
        size_t idx = (size_t)(cm0 + mf * 16 + r) * ldc + cn0 + nf * 16;
        if (OBF)
          ((unsigned short*)Cv)[idx] = f2bf(acc[mf][nf][r]);
        else
          ((float*)Cv)[idx] = acc[mf][nf][r];
      }
}

// 4-way split-K reduce: out = p0+p1+p2+p3 (fp32, vectorized)
__global__ __launch_bounds__(256) void out_reduce(const float* __restrict__ p0,
                                                  const float* __restrict__ p1,
                                                  const float* __restrict__ p2,
                                                  const float* __restrict__ p3,
                                                  float* __restrict__ out) {
  size_t t = ((size_t)blockIdx.x * 256 + threadIdx.x) * 4;
  float4 a = *reinterpret_cast<const float4*>(p0 + t);
  float4 b = *reinterpret_cast<const float4*>(p1 + t);
  float4 c = *reinterpret_cast<const float4*>(p2 + t);
  float4 d = *reinterpret_cast<const float4*>(p3 + t);
  float4 r;
  r.x = a.x + b.x + c.x + d.x;
  r.y = a.y + b.y + c.y + d.y;
  r.z = a.z + b.z + c.z + d.z;
  r.w = a.w + b.w + c.w + d.w;
  *reinterpret_cast<float4*>(out + t) = r;
}

// ---------------------------------------------------------------------------
// bf16 MFMA GEMM (m97 structure) — kept for dt GEMM (K=128).
// EPI==1: softplus(c + bias[n]).  OBF==1: write bf16, else fp32.
// ---------------------------------------------------------------------------
template <int EPI, int OBF>
__global__ __launch_bounds__(256) void gemm_bf16_nt(const unsigned short* __restrict__ A, int lda,
                                                    const unsigned short* __restrict__ W, int ldw,
                                                    void* __restrict__ Cv, int ldc, int Kdim,
                                                    const float* __restrict__ bias) {
  __shared__ unsigned short As[128 * 32];
  __shared__ unsigned short Bs[128 * 32];
  const int tid = threadIdx.x;
  const int lane = tid & 63;
  const int wave = tid >> 6;
  const int wr = wave >> 1, wc = wave & 1;
  const int bm = blockIdx.y * 128, bn = blockIdx.x * 128;

  f32x4 acc[4][4];
#pragma unroll
  for (int mt = 0; mt < 4; mt++)
#pragma unroll
    for (int nt = 0; nt < 4; nt++) acc[mt][nt] = (f32x4){0.f, 0.f, 0.f, 0.f};

  const int srow = tid >> 2;
  const int scol = (tid & 3) * 8;
  const unsigned short* Ag = A + (size_t)(bm + srow) * lda + scol;
  const unsigned short* Wg = W + (size_t)(bn + srow) * ldw + scol;
  unsigned short* Al = As + tid * 8;
  unsigned short* Wl = Bs + tid * 8;

  const unsigned short* aRd = As + (wr * 64 + (lane & 15)) * 32 + (lane >> 4) * 8;
  const unsigned short* bRd = Bs + (wc * 64 + (lane & 15)) * 32 + (lane >> 4) * 8;

  for (int k0 = 0; k0 < Kdim; k0 += 32) {
    __syncthreads();
    gload16(Ag + k0, Al);
    gload16(Ag + k0 + (size_t)64 * lda, Al + 64 * 32);
    gload16(Wg + k0, Wl);
    gload16(Wg + k0 + (size_t)64 * ldw, Wl + 64 * 32);
    __syncthreads();
    s16x8 af[4], bw[4];
#pragma unroll
    for (int mt = 0; mt < 4; mt++) af[mt] = *reinterpret_cast<const s16x8*>(aRd + mt * 16 * 32);
#pragma unroll
    for (int nt = 0; nt < 4; nt++) bw[nt] = *reinterpret_cast<const s16x8*>(bRd + nt * 16 * 32);
#pragma unroll
    for (int mt = 0; mt < 4; mt++)
#pragma unroll
      for (int nt = 0; nt < 4; nt++)
        acc[mt][nt] = __builtin_amdgcn_mfma_f32_16x16x32_bf16(af[mt], bw[nt], acc[mt][nt], 0, 0, 0);
  }

  const int cm0 = bm + wr * 64 + (lane >> 4) * 4;
  const int cn0 = bn + wc * 64 + (lane & 15);
#pragma unroll
  for (int mt = 0; mt < 4; mt++)
#pragma unroll
    for (int nt = 0; nt < 4; nt++)
#pragma unroll
      for (int r = 0; r < 4; r++) {
        float c = acc[mt][nt][r];
        int n = cn0 + nt * 16;
        if (EPI == 1) {
          float xx = c + bias[n];
          c = (xx > 20.f) ? xx : log1pf(__expf(xx));
        }
        size_t idx = (size_t)(cm0 + mt * 16 + r) * ldc + n;
        if (OBF)
          ((unsigned short*)Cv)[idx] = f2bf(c);
        else
          ((float*)Cv)[idx] = c;
      }
}

// ---------------------------------------------------------------------------
// Skinny ssm GEMM: part[ks][m][n] = sum_{k in chunk ks} u[m,k]*w[n,k]
// ---------------------------------------------------------------------------
__global__ __launch_bounds__(256) void ssm_bf16_kernel(const unsigned short* __restrict__ ub,
                                                       const unsigned short* __restrict__ wb,
                                                       float* __restrict__ part) {
  const int tid = threadIdx.x;
  const int lane = tid & 63;
  const int wave = tid >> 6;
  const int mt = blockIdx.x;
  const int ks = blockIdx.y;
  const int r15 = lane & 15;
  const int kg = (lane >> 4) * 8;

  const unsigned short* Arow = ub + (size_t)(mt * 64 + wave * 16 + r15) * Ic + ks * KCH + kg;
  const unsigned short* Brow = wb + (size_t)r15 * Ic + ks * KCH + kg;

  f32x4 acc[10];
#pragma unroll
  for (int nt = 0; nt < 10; nt++) acc[nt] = (f32x4){0.f, 0.f, 0.f, 0.f};

#pragma unroll 2
  for (int kk = 0; kk < KCH; kk += 32) {
    s16x8 af = *reinterpret_cast<const s16x8*>(Arow + kk);
#pragma unroll
    for (int nt = 0; nt < 10; nt++) {
      s16x8 bf = *reinterpret_cast<const s16x8*>(Brow + (size_t)nt * 16 * Ic + kk);
      acc[nt] = __builtin_amdgcn_mfma_f32_16x16x32_bf16(af, bf, acc[nt], 0, 0, 0);
    }
  }

  const int m0 = mt * 64 + wave * 16 + (lane >> 4) * 4;
  float* po = part + ((size_t)ks * Mrows + m0) * Pc;
#pragma unroll
  for (int nt = 0; nt < 10; nt++)
#pragma unroll
    for (int r = 0; r < 4; r++)
      po[(size_t)r * Pc + nt * 16 + r15] = acc[nt][r];
}

__global__ __launch_bounds__(256) void ssm_reduce(const float* __restrict__ part,
                                                  float* __restrict__ ssm,
                                                  unsigned short* __restrict__ tsb) {
  int t = blockIdx.x * 256 + threadIdx.x;
  float s = 0.f;
#pragma unroll
  for (int ks = 0; ks < KS; ks++) s += part[(size_t)ks * Mrows * Pc + t];
  ssm[t] = s;
  int m = t / Pc, n = t - m * Pc;
  if (n < Rc) tsb[(size_t)m * Rc + n] = f2bf(s);
}

// ---------------------------------------------------------------------------
// Causal depthwise conv (K=4) + silu; bf16 in/out.
// ---------------------------------------------------------------------------
__global__ __launch_bounds__(256) void conv_silu_kernel(const unsigned short* __restrict__ projb,
                                                        const float* __restrict__ cw,
                                                        const float* __restrict__ cb,
                                                        unsigned short* __restrict__ ub) {
  int t = blockIdx.x * 256 + threadIdx.x;
  int i = t & (Ic - 1);
  int m = t >> 12;
  int l = m & (Lc - 1);
  float4 w4 = *reinterpret_cast<const float4*>(&cw[i * 4]);
  float wk[4] = {w4.x, w4.y, w4.z, w4.w};
  float acc = cb[i];
#pragma unroll
  for (int k = 0; k < 4; k++) {
    int ll = l - 3 + k;
    if (ll >= 0) acc = fmaf(wk[k], bf2f(projb[(size_t)(m - 3 + k) * TWOI + i]), acc);
  }
  float s = acc / (1.f + __expf(-acc));
  ub[(size_t)m * Ic + i] = f2bf(s);
}

// ---------------------------------------------------------------------------
// Scan pass 1
// ---------------------------------------------------------------------------
__global__ __launch_bounds__(256) void scan_pass1(const float* __restrict__ dt,
                                                  const unsigned short* __restrict__ ub,
                                                  const float* __restrict__ ssm,
                                                  const float* __restrict__ A_log,
                                                  float* __restrict__ sc1) {
  constexpr int IB = Ic / 256;
  int ib = blockIdx.x % IB;
  int c = (blockIdx.x / IB) % NCH;
  int b = blockIdx.x / (IB * NCH);
  int i = ib * 256 + threadIdx.x;

  float Ac[Nc];
#pragma unroll
  for (int n = 0; n < Nc; n++) Ac[n] = -__expf(A_log[i * Nc + n]);
  float Ap[Nc], h[Nc];
#pragma unroll
  for (int n = 0; n < Nc; n++) { Ap[n] = 1.f; h[n] = 0.f; }

  int l0 = c * CL;
  for (int l = l0; l < l0 + CL; l++) {
    int m = b * Lc + l;
    float dtv = dt[(size_t)m * Ic + i];
    float uv = bf2f(ub[(size_t)m * Ic + i]);
    float du = dtv * uv;
#pragma unroll
    for (int n = 0; n < Nc; n++) {
      float Bv = ssm[m * Pc + Rc + n];
      float dA = __expf(dtv * Ac[n]);
      h[n] = fmaf(dA, h[n], du * Bv);
      Ap[n] *= dA;
    }
  }
  size_t off = ((size_t)(b * Ic + i) * NCH + c) * 32;
#pragma unroll
  for (int n = 0; n < Nc; n++) {
    sc1[off + n] = Ap[n];
    sc1[off + 16 + n] = h[n];
  }
}

__global__ __launch_bounds__(256) void scan_mid(const float* __restrict__ sc1,
                                                float* __restrict__ sc2) {
  int t = blockIdx.x * 256 + threadIdx.x;
  int n = t & 15;
  int bi = t >> 4;
  float h = 0.f;
  size_t base = (size_t)bi * NCH;
  for (int c = 0; c < NCH; c++) {
    sc2[(base + c) * 16 + n] = h;
    float Ap = sc1[(base + c) * 32 + n];
    float he = sc1[(base + c) * 32 + 16 + n];
    h = fmaf(Ap, h, he);
  }
}

// ---------------------------------------------------------------------------
// Scan pass 3
// ---------------------------------------------------------------------------
__global__ __launch_bounds__(256) void scan_pass3(const float* __restrict__ dt,
                                                  const unsigned short* __restrict__ ub,
                                                  const float* __restrict__ ssm,
                                                  const float* __restrict__ A_log,
                                                  const float* __restrict__ Dp,
                                                  const float* __restrict__ sc2,
                                                  const unsigned short* __restrict__ projb,
                                                  unsigned short* __restrict__ yb) {
  constexpr int IB = Ic / 256;
  int ib = blockIdx.x % IB;
  int c = (blockIdx.x / IB) % NCH;
  int b = blockIdx.x / (IB * NCH);
  int i = ib * 256 + threadIdx.x;

  float Ac[Nc];
#pragma unroll
  for (int n = 0; n < Nc; n++) Ac[n] = -__expf(A_log[i * Nc + n]);
  float h[Nc];
  size_t hoff = ((size_t)(b * Ic + i) * NCH + c) * 16;
#pragma unroll
  for (int n = 0; n < Nc; n++) h[n] = sc2[hoff + n];
  float Dv = Dp[i];

  int l0 = c * CL;
  for (int l = l0; l < l0 + CL; l++) {
    int m = b * Lc + l;
    float dtv = dt[(size_t)m * Ic + i];
    float uv = bf2f(ub[(size_t)m * Ic + i]);
    float du = dtv * uv;
    float acc = Dv * uv;
#pragma unroll
    for (int n = 0; n < Nc; n++) {
      float Bv = ssm[m * Pc + Rc + n];
      float Cv = ssm[m * Pc + Rc + Nc + n];
      float dA = __expf(dtv * Ac[n]);
      h[n] = fmaf(dA, h[n], du * Bv);
      acc = fmaf(h[n], Cv, acc);
    }
    float g = bf2f(projb[(size_t)m * TWOI + Ic + i]);
    float sg = g / (1.f + __expf(-g));
    yb[(size_t)m * Ic + i] = f2bf(acc * sg);
  }
}

// ---------------------------------------------------------------------------
extern "C" void kernel_launch(void* const* d_in, const int* in_sizes, int n_in,
                              void* d_out, int out_size, void* d_ws, size_t ws_size,
                              hipStream_t stream) {
  const float* x = (const float*)d_in[0];
  const float* in_proj_w = (const float*)d_in[1];
  const float* conv_w = (const float*)d_in[2];
  const float* conv_b = (const float*)d_in[3];
  const float* x_proj_w = (const float*)d_in[4];
  const float* dt_proj_w = (const float*)d_in[5];
  const float* dt_proj_b = (const float*)d_in[6];
  const float* A_log = (const float*)d_in[7];
  const float* Dp = (const float*)d_in[8];
  const float* out_proj_w = (const float*)d_in[9];
  float* out = (float*)d_out;

  // Workspace layout (overlays; lifetimes disjoint in stream order):
  char* base = (char*)d_ws;
  unsigned short* projb = (unsigned short*)base; base += (size_t)Mrows * TWOI * 2;  // 33.55 MB
  unsigned short* ub = (unsigned short*)base;    base += (size_t)Mrows * Ic * 2;    // 16.78 MB
  float* ssm = (float*)base;                     base += (size_t)Mrows * Pc * 4;    // 1.31 MB
  unsigned short* tsb = (unsigned short*)base;   base += (size_t)Mrows * Rc * 2;    // 0.52 MB
  char* dtb = base;                              base += (size_t)Mrows * Ic * 4;    // 33.55 MB
  float* dt = (float*)dtb;
  float* part = (float*)dtb;                   // [KS][M][Pc], dead before dt
  unsigned short* owb = (unsigned short*)dtb;  // out_proj bf16, overlays dt after scan3
  char* xbb = base;                              base += (size_t)Mrows * Hc * 2;    // 8.39 MB
  unsigned short* xb = (unsigned short*)xbb;
  unsigned short* wb160 = (unsigned short*)xbb;
  unsigned short* dtwb = (unsigned short*)(xbb + 2 * 1024 * 1024);
  char* wbase = base;                            base += (size_t)TWOI * Hc * 2;     // 33.55 MB
  unsigned short* wb = (unsigned short*)wbase;
  float* sc1 = (float*)wbase;
  unsigned short* yb = (unsigned short*)wbase;
  float* sc2 = (float*)(wbase + (size_t)Bc * Ic * NCH * 32 * 4);
  size_t need = (size_t)(base - (char*)d_ws);
  if (ws_size < need) return;

  // Split-K partials for the out GEMM (all regions dead after scan_pass3):
  // quarter size Q = 2048*2048*4 = 16.78 MB
  const size_t Q = (size_t)Mrows * Hc * 4;
  float* op0 = (float*)((char*)projb);            // projb[0 .. Q)
  float* op1 = (float*)((char*)projb + Q);        // projb[Q .. 2Q)  (projb is 2Q)
  float* op2 = (float*)((char*)ub);               // ub+ssm+tsb span (18.6 MB > Q)
  float* op3 = (float*)(dtb + Q);                 // dtb second half (owb uses first Q)

  dim3 blk(256);

  // 0) bf16 conversions for proj GEMM
  cvt_f32_bf16<<<(Mrows * (size_t)Hc / 8 + 255) / 256, blk, 0, stream>>>(x, xb, Mrows * (size_t)Hc / 8);
  cvt_f32_bf16<<<((size_t)TWOI * Hc / 8 + 255) / 256, blk, 0, stream>>>(in_proj_w, wb, (size_t)TWOI * Hc / 8);

  // 1) proj = x @ in_proj_w^T (256^2 deep-pipelined bf16 GEMM, bf16 out)
  gemm256_bf16_nt<1><<<dim3(TWOI / 256, Mrows / 256, 1), dim3(512), 0, stream>>>(
      xb, Hc, wb, Hc, projb, projb, projb, projb, TWOI, Hc);

  // 1b) small-weight conversions (into dead xb region)
  cvt_f32_bf16<<<((size_t)Pc * Ic / 8 + 255) / 256, blk, 0, stream>>>(x_proj_w, wb160, (size_t)Pc * Ic / 8);
  cvt_f32_bf16<<<((size_t)Ic * Rc / 8 + 255) / 256, blk, 0, stream>>>(dt_proj_w, dtwb, (size_t)Ic * Rc / 8);

  // 2) conv + silu -> ub (bf16)
  conv_silu_kernel<<<(size_t)Mrows * Ic / 256, blk, 0, stream>>>(projb, conv_w, conv_b, ub);

  // 3) ssm = u @ x_proj_w^T (split-K bf16) -> ssm f32 + ts bf16
  ssm_bf16_kernel<<<dim3(Mrows / 64, KS), blk, 0, stream>>>(ub, wb160, part);
  ssm_reduce<<<Mrows * Pc / 256, blk, 0, stream>>>(part, ssm, tsb);

  // 4) dt = softplus(ts @ dt_proj_w^T + b) (bf16 MFMA, K=128, fp32 out)
  gemm_bf16_nt<1, 0><<<dim3(Ic / 128, Mrows / 128), blk, 0, stream>>>(
      tsb, Rc, dtwb, Rc, dt, Ic, Rc, dt_proj_b);

  // 5-7) chunked scan + fused epilogue -> yb (bf16)
  scan_pass1<<<Bc * NCH * (Ic / 256), blk, 0, stream>>>(dt, ub, ssm, A_log, sc1);
  scan_mid<<<Bc * Ic * Nc / 256, blk, 0, stream>>>(sc1, sc2);
  scan_pass3<<<Bc * NCH * (Ic / 256), blk, 0, stream>>>(dt, ub, ssm, A_log, Dp, sc2, projb, yb);

  // 7b) out_proj -> bf16 (overlays dt first half, dead after scan3)
  cvt_f32_bf16<<<((size_t)Hc * Ic / 8 + 255) / 256, blk, 0, stream>>>(out_proj_w, owb, (size_t)Hc * Ic / 8);

  // 8) out = y @ out_proj_w^T (256^2 kernel, split-K=4, fp32 partials + reduce)
  gemm256_bf16_nt<0><<<dim3(Hc / 256, Mrows / 256, 4), dim3(512), 0, stream>>>(
      yb, Ic, owb, Ic, op0, op1, op2, op3, Hc, Ic / 4);
  out_reduce<<<(Mrows * (size_t)Hc / 4) / 256, blk, 0, stream>>>(op0, op1, op2, op3, out);
}